// Round 16
// baseline (392.833 us; speedup 1.0000x reference)
//
#include <hip/hip_runtime.h>
#include <hip/hip_bf16.h>

#define N_NODES 50000
#define E0      800000
#define ETOT    850000

typedef __bf16 bf16x8 __attribute__((ext_vector_type(8)));
typedef float  f32x4  __attribute__((ext_vector_type(4)));
typedef ushort u16x8  __attribute__((ext_vector_type(8)));
union B8 { u16x8 u; bf16x8 b; };

static __device__ __forceinline__ float b2f(ushort u) {
    union { uint u; float f; } x; x.u = ((uint)u) << 16; return x.f;
}
static __device__ __forceinline__ ushort f2bf(float f) {
    uint u = __builtin_bit_cast(uint, f);
    uint r = (u + 0x7FFFu + ((u >> 16) & 1u)) >> 16;   // RNE; inputs finite
    return (ushort)r;
}

// ---------------- CSR build ----------------

__global__ __launch_bounds__(256) void k_deg(const int* __restrict__ ei, int* __restrict__ deg) {
    int e = blockIdx.x * 256 + threadIdx.x;
    if (e >= ETOT) return;
    int dst = (e < E0) ? ei[E0 + e] : (e - E0);
    atomicAdd(&deg[dst], 1);
}

__global__ __launch_bounds__(256) void k_scan1(const int* __restrict__ deg, int* __restrict__ offs,
                                               int* __restrict__ bsum) {
    __shared__ int buf[256];
    int tid = threadIdx.x;
    int i = blockIdx.x * 256 + tid;
    int v = (i < N_NODES) ? deg[i] : 0;
    buf[tid] = v;
    __syncthreads();
    for (int off = 1; off < 256; off <<= 1) {
        int t = (tid >= off) ? buf[tid - off] : 0;
        __syncthreads();
        buf[tid] += t;
        __syncthreads();
    }
    if (i < N_NODES) offs[i + 1] = buf[tid];
    if (tid == 255) bsum[blockIdx.x] = buf[255];
}

__global__ __launch_bounds__(256) void k_scan2(int* __restrict__ bsum, int nb) {
    __shared__ int buf[256];
    int tid = threadIdx.x;
    int v = (tid < nb) ? bsum[tid] : 0;
    buf[tid] = v;
    __syncthreads();
    for (int off = 1; off < 256; off <<= 1) {
        int t = (tid >= off) ? buf[tid - off] : 0;
        __syncthreads();
        buf[tid] += t;
        __syncthreads();
    }
    if (tid < nb) bsum[tid] = buf[tid] - v;
}

// also fills cursor (saves a kernel)
__global__ __launch_bounds__(256) void k_scan3(int* __restrict__ offs, const int* __restrict__ bsum,
                                               int* __restrict__ cursor) {
    int tid = threadIdx.x;
    int i = blockIdx.x * 256 + tid;
    if (i < N_NODES) {
        int v = offs[i + 1] + bsum[blockIdx.x];
        offs[i + 1] = v;
        cursor[i + 1] = v;
    }
    if (i == 0) { offs[0] = 0; cursor[0] = 0; }
}

__global__ __launch_bounds__(256) void k_scatter(const int* __restrict__ ei, int* __restrict__ cursor,
                                                 int* __restrict__ esrc) {
    int e = blockIdx.x * 256 + threadIdx.x;
    if (e >= ETOT) return;
    int src, dst;
    if (e < E0) { src = ei[e]; dst = ei[E0 + e]; }
    else        { src = e - E0; dst = src; }
    int pos = atomicAdd(&cursor[dst], 1);
    esrc[pos] = src;
}

// W [K][N] fp32 -> Wt_hi/Wt_lo [N][K] bf16 (tiny)
__global__ __launch_bounds__(256) void k_splitT(const float* __restrict__ W, ushort* __restrict__ th,
                                                ushort* __restrict__ tl, int K, int N) {
    int i = blockIdx.x * 256 + threadIdx.x;
    if (i >= K * N) return;
    int n = i / K, k = i - n * K;
    float v = W[(size_t)k * N + n];
    ushort h = f2bf(v);
    th[(size_t)n * K + k] = h;
    tl[(size_t)n * K + k] = f2bf(v - b2f(h));
}

// w1s = W1 @ a_src1, w1d = W1 @ a_dst1, w2s = W2 @ a_src2, w2d = W2 @ a_dst2
// (alpha GEMV refactor: as = h.a_src = x.(W1 a_src))  1024 waves total.
__global__ __launch_bounds__(256) void k_wvec(const float* __restrict__ W1, const float* __restrict__ s1v,
                                              const float* __restrict__ d1v, const float* __restrict__ W2,
                                              const float* __restrict__ s2v, const float* __restrict__ d2v,
                                              float* __restrict__ w1s, float* __restrict__ w1d,
                                              float* __restrict__ w2s, float* __restrict__ w2d) {
    int gw = (blockIdx.x * 256 + threadIdx.x) >> 6;
    int lane = threadIdx.x & 63;
    int vec = gw >> 8, kk = gw & 255;
    float a = 0.f;
    if (vec == 0)      { for (int n = lane; n < 256; n += 64) a += W1[(size_t)kk * 256 + n] * s1v[n]; }
    else if (vec == 1) { for (int n = lane; n < 256; n += 64) a += W1[(size_t)kk * 256 + n] * d1v[n]; }
    else if (vec == 2) { for (int n = lane; n < 128; n += 64) a += W2[(size_t)kk * 128 + n] * s2v[n]; }
    else               { for (int n = lane; n < 128; n += 64) a += W2[(size_t)kk * 128 + n] * d2v[n]; }
    for (int o = 32; o; o >>= 1) a += __shfl_down(a, o);
    if (lane == 0) {
        if (vec == 0) w1s[kk] = a;
        else if (vec == 1) w1d[kk] = a;
        else if (vec == 2) w2s[kk] = a;
        else w2d[kk] = a;
    }
}

// one wave per row: x -> bf16 xb, plus layer1 alphas as1 = x.w1s, ad1 = x.w1d
__global__ __launch_bounds__(256) void k_prep1(const float* __restrict__ x, const float* __restrict__ w1s,
                                               const float* __restrict__ w1d, ushort* __restrict__ xb,
                                               float* __restrict__ as1, float* __restrict__ ad1) {
    int gw = (blockIdx.x * 256 + threadIdx.x) >> 6;
    int lane = threadIdx.x & 63;
    if (gw >= N_NODES) return;
    float4 v = *(const float4*)(x + (size_t)gw * 256 + lane * 4);
    ushort4 h;
    h.x = f2bf(v.x); h.y = f2bf(v.y); h.z = f2bf(v.z); h.w = f2bf(v.w);
    *(ushort4*)(xb + (size_t)gw * 256 + lane * 4) = h;
    float4 cs = *(const float4*)(w1s + lane * 4);
    float4 cd = *(const float4*)(w1d + lane * 4);
    float s = v.x * cs.x + v.y * cs.y + v.z * cs.z + v.w * cs.w;
    float d = v.x * cd.x + v.y * cd.y + v.z * cd.z + v.w * cd.w;
    for (int o = 32; o; o >>= 1) { s += __shfl_down(s, o); d += __shfl_down(d, o); }
    if (lane == 0) { as1[gw] = s; ad1[gw] = d; }
}

// ---------------- MFMA GEMM: A bf16 (pre-rounded), B hi/lo LDS dbuf ----------------
// [R13 config — best measured; frozen]

__global__ __launch_bounds__(256, 2) void k_gemm_mfma(const ushort* __restrict__ Ab,
                                                      const ushort* __restrict__ Bth,
                                                      const ushort* __restrict__ Btl,
                                                      ushort* __restrict__ Cb, int M, int Nn) {
    constexpr int K = 256;
    __shared__ ushort lds[2][2][8][128][8];      // 64 KB
    int tid = threadIdx.x;
    int wid = tid >> 6, lane = tid & 63;
    int wr = wid >> 1, wc = wid & 1;
    int bm = blockIdx.x * 128, bn = blockIdx.y * 128;
    int lr = lane & 15, lg = lane >> 4;

    int sa = tid >> 7, scol = tid & 127;
    const ushort* sb = (sa ? Btl : Bth) + (size_t)(bn + scol) * K;

    const ushort* Ap[4];
#pragma unroll
    for (int m = 0; m < 4; ++m) {
        int row = bm + wr * 64 + m * 16 + lr;
        if (row >= M) row = M - 1;
        Ap[m] = Ab + (size_t)row * K + lg * 8;
    }

    f32x4 acc[4][4] = {};
    u16x8 sv[8];
    bf16x8 aH[2][4];

#pragma unroll
    for (int c = 0; c < 8; ++c) sv[c] = *(const u16x8*)(sb + c * 8);
#pragma unroll
    for (int m = 0; m < 4; ++m) {
        aH[0][m] = *(const bf16x8*)(Ap[m]);
        aH[1][m] = *(const bf16x8*)(Ap[m] + 32);
    }
#pragma unroll
    for (int c = 0; c < 8; ++c) *(u16x8*)&lds[0][sa][c][scol][0] = sv[c];
    __syncthreads();

#pragma unroll
    for (int s = 0; s < 8; ++s) {
        const int w = s >> 1, buf = w & 1, kk = s & 1;
        if (kk == 0 && w < 3) {
#pragma unroll
            for (int c = 0; c < 8; ++c) sv[c] = *(const u16x8*)(sb + (w + 1) * 64 + c * 8);
        }
        bf16x8 bh[4], bl[4];
#pragma unroll
        for (int n = 0; n < 4; ++n) {
            int col = wc * 64 + n * 16 + lr;
            B8 th, tl2;
            th.u = *(const u16x8*)&lds[buf][0][kk * 4 + lg][col][0];
            tl2.u = *(const u16x8*)&lds[buf][1][kk * 4 + lg][col][0];
            bh[n] = th.b; bl[n] = tl2.b;
        }
        bf16x8 ah[4];
#pragma unroll
        for (int m = 0; m < 4; ++m) ah[m] = aH[s & 1][m];
        if (s < 6) {
#pragma unroll
            for (int m = 0; m < 4; ++m) aH[s & 1][m] = *(const bf16x8*)(Ap[m] + (s + 2) * 32);
        }
#pragma unroll
        for (int m = 0; m < 4; ++m)
#pragma unroll
            for (int n = 0; n < 4; ++n) {
                acc[m][n] = __builtin_amdgcn_mfma_f32_16x16x32_bf16(ah[m], bh[n], acc[m][n], 0, 0, 0);
                acc[m][n] = __builtin_amdgcn_mfma_f32_16x16x32_bf16(ah[m], bl[n], acc[m][n], 0, 0, 0);
            }
        if (kk == 1 && w < 3) {
#pragma unroll
            for (int c = 0; c < 8; ++c) *(u16x8*)&lds[buf ^ 1][sa][c][scol][0] = sv[c];
            __syncthreads();
        }
    }
    // C/D layout: col = lane&15, row = (lane>>4)*4 + reg   [m89-verified]
#pragma unroll
    for (int m = 0; m < 4; ++m)
#pragma unroll
        for (int r = 0; r < 4; ++r) {
            int row = bm + wr * 64 + m * 16 + lg * 4 + r;
            if (row < M) {
#pragma unroll
                for (int n = 0; n < 4; ++n) {
                    int col = bn + wc * 64 + n * 16 + lr;
                    Cb[(size_t)row * Nn + col] = f2bf(acc[m][n][r]);
                }
            }
        }
}

// ---- fused online-softmax aggregation: software-pipelined 8-edge batches ----
// A2 (F=256 only): epilogue computes layer2 alphas as2 = r.w2s, ad2 = r.w2d
// WB: write RNE-bf16 copy of result (next layer GEMM A).

#define AGG_LOAD(RR, EV, RW, KK) do {                                              \
    _Pragma("unroll") for (int q = 0; q < 8; ++q) RR[q] = esrc[(KK) + q];          \
    _Pragma("unroll") for (int q = 0; q < 8; ++q) EV[q] = as[RR[q]];               \
    _Pragma("unroll") for (int q = 0; q < 8; ++q) {                                \
        if constexpr (V == 4) {                                                    \
            ushort4 v = *(const ushort4*)(H + (size_t)RR[q] * F + lane * 4);       \
            RW[q][0] = b2f(v.x); RW[q][1] = b2f(v.y);                              \
            RW[q][2] = b2f(v.z); RW[q][3] = b2f(v.w);                              \
        } else {                                                                   \
            ushort2 v = *(const ushort2*)(H + (size_t)RR[q] * F + lane * 2);       \
            RW[q][0] = b2f(v.x); RW[q][1] = b2f(v.y);                              \
        }                                                                          \
    }                                                                              \
} while (0)

#define AGG_PROC(RR, EV, RW) do {                                                  \
    float em = -1e30f;                                                             \
    _Pragma("unroll") for (int q = 0; q < 8; ++q) {                                \
        float e = EV[q] + adi; e = e > 0.f ? e : 0.2f * e;                         \
        EV[q] = e; em = fmaxf(em, e);                                              \
    }                                                                              \
    if (em > m + THR) {                                                            \
        float sc = __expf(m - em);                                                 \
        ssum *= sc;                                                                \
        _Pragma("unroll") for (int j = 0; j < V; ++j) acc[j] *= sc;                \
        m = em;                                                                    \
    }                                                                              \
    float w[8];                                                                    \
    _Pragma("unroll") for (int q = 0; q < 8; ++q) w[q] = __expf(EV[q] - m);        \
    _Pragma("unroll") for (int q = 0; q < 8; ++q) ssum += w[q];                    \
    _Pragma("unroll") for (int j = 0; j < V; ++j) {                                \
        float a = acc[j];                                                          \
        _Pragma("unroll") for (int q = 0; q < 8; ++q) a += w[q] * RW[q][j];        \
        acc[j] = a;                                                                \
    }                                                                              \
} while (0)

template <int F, bool RELU, bool WB, bool A2>
__global__ __launch_bounds__(256) void k_aggf(const int* __restrict__ offs, const int* __restrict__ esrc,
                                              const float* __restrict__ as, const float* __restrict__ ad,
                                              const ushort* __restrict__ H, const float* __restrict__ bias,
                                              float* __restrict__ out, ushort* __restrict__ hb,
                                              const float* __restrict__ w2s, const float* __restrict__ w2d,
                                              float* __restrict__ as2, float* __restrict__ ad2) {
    constexpr int V = F / 64;
    constexpr float THR = 8.f;
    int gw = (blockIdx.x * 256 + threadIdx.x) >> 6;
    int lane = threadIdx.x & 63;
    if (gw >= N_NODES) return;
    int s0 = offs[gw], s1 = offs[gw + 1];
    float adi = ad[gw];
    float m = -1e30f, ssum = 0.f;
    float acc[V] = {};

    int nb = (s1 - s0) >> 3;
    int k = s0;
    int rrA[8]; float evA[8]; float rwA[8][V];
    int rrB[8]; float evB[8]; float rwB[8][V];
    if (nb > 0) AGG_LOAD(rrA, evA, rwA, k);
    for (int b = 0; b < nb; ++b) {
        if ((b & 1) == 0) {
            if (b + 1 < nb) AGG_LOAD(rrB, evB, rwB, k + 8);
            AGG_PROC(rrA, evA, rwA);
        } else {
            if (b + 1 < nb) AGG_LOAD(rrA, evA, rwA, k + 8);
            AGG_PROC(rrB, evB, rwB);
        }
        k += 8;
    }
    for (; k + 3 < s1; k += 4) {
        int rr[4];
#pragma unroll
        for (int q = 0; q < 4; ++q) rr[q] = esrc[k + q];
        float ev[4];
#pragma unroll
        for (int q = 0; q < 4; ++q) ev[q] = as[rr[q]];
        float rows[4][V];
#pragma unroll
        for (int q = 0; q < 4; ++q) {
            if constexpr (V == 4) {
                ushort4 v = *(const ushort4*)(H + (size_t)rr[q] * F + lane * 4);
                rows[q][0] = b2f(v.x); rows[q][1] = b2f(v.y); rows[q][2] = b2f(v.z); rows[q][3] = b2f(v.w);
            } else {
                ushort2 v = *(const ushort2*)(H + (size_t)rr[q] * F + lane * 2);
                rows[q][0] = b2f(v.x); rows[q][1] = b2f(v.y);
            }
        }
        float em = -1e30f;
#pragma unroll
        for (int q = 0; q < 4; ++q) {
            float e = ev[q] + adi;
            e = e > 0.f ? e : 0.2f * e;
            ev[q] = e;
            em = fmaxf(em, e);
        }
        if (em > m + THR) {
            float sc = __expf(m - em);
            ssum *= sc;
#pragma unroll
            for (int j = 0; j < V; ++j) acc[j] *= sc;
            m = em;
        }
        float w[4];
#pragma unroll
        for (int q = 0; q < 4; ++q) w[q] = __expf(ev[q] - m);
#pragma unroll
        for (int q = 0; q < 4; ++q) ssum += w[q];
#pragma unroll
        for (int j = 0; j < V; ++j) {
            float a = acc[j];
#pragma unroll
            for (int q = 0; q < 4; ++q) a += w[q] * rows[q][j];
            acc[j] = a;
        }
    }
    for (; k < s1; ++k) {
        int r0 = esrc[k];
        float row0[V];
        if constexpr (V == 4) {
            ushort4 v0 = *(const ushort4*)(H + (size_t)r0 * F + lane * 4);
            row0[0] = b2f(v0.x); row0[1] = b2f(v0.y); row0[2] = b2f(v0.z); row0[3] = b2f(v0.w);
        } else {
            ushort2 v0 = *(const ushort2*)(H + (size_t)r0 * F + lane * 2);
            row0[0] = b2f(v0.x); row0[1] = b2f(v0.y);
        }
        float e0 = as[r0] + adi; e0 = e0 > 0.f ? e0 : 0.2f * e0;
        if (e0 > m + THR) {
            float sc = __expf(m - e0);
            ssum *= sc;
#pragma unroll
            for (int j = 0; j < V; ++j) acc[j] *= sc;
            m = e0;
        }
        float w0 = __expf(e0 - m);
        ssum += w0;
#pragma unroll
        for (int j = 0; j < V; ++j) acc[j] += w0 * row0[j];
    }
    float inv = 1.f / ssum;
    float r[V];
#pragma unroll
    for (int j = 0; j < V; ++j) {
        r[j] = acc[j] * inv + bias[lane * V + j];
        if (RELU) r[j] = fmaxf(r[j], 0.f);
    }
    if (V == 4) *(float4*)(out + (size_t)gw * F + lane * 4) = make_float4(r[0], r[1], r[2], r[3]);
    else        *(float2*)(out + (size_t)gw * F + lane * 2) = make_float2(r[0], r[1]);
    if constexpr (WB && V == 4) {
        ushort4 h4;
        h4.x = f2bf(r[0]); h4.y = f2bf(r[1]); h4.z = f2bf(r[2]); h4.w = f2bf(r[3]);
        *(ushort4*)(hb + (size_t)gw * F + lane * 4) = h4;
    }
    if constexpr (A2 && V == 4) {
        float4 cs = *(const float4*)(w2s + lane * 4);
        float4 cd = *(const float4*)(w2d + lane * 4);
        float s2 = r[0] * cs.x + r[1] * cs.y + r[2] * cs.z + r[3] * cs.w;
        float d2 = r[0] * cd.x + r[1] * cd.y + r[2] * cd.z + r[3] * cd.w;
        for (int o = 32; o; o >>= 1) { s2 += __shfl_down(s2, o); d2 += __shfl_down(d2, o); }
        if (lane == 0) { as2[gw] = s2; ad2[gw] = d2; }
    }
}

// ---------------- launch ----------------

static inline size_t al256(size_t x) { return (x + 255) & ~(size_t)255; }

extern "C" void kernel_launch(void* const* d_in, const int* in_sizes, int n_in,
                              void* d_out, int out_size, void* d_ws, size_t ws_size,
                              hipStream_t stream) {
    const float* x   = (const float*)d_in[0];
    const int*   ei  = (const int*)d_in[1];
    const float* W1  = (const float*)d_in[2];
    const float* as1 = (const float*)d_in[3];
    const float* ad1 = (const float*)d_in[4];
    const float* b1  = (const float*)d_in[5];
    const float* W2  = (const float*)d_in[6];
    const float* as2 = (const float*)d_in[7];
    const float* ad2 = (const float*)d_in[8];
    const float* b2  = (const float*)d_in[9];

    float* out_x2 = (float*)d_out;                          // [50000,128]
    float* out_h  = (float*)d_out + (size_t)N_NODES * 128;  // [50000,256] fp32

    const size_t NM256 = (size_t)N_NODES * 256 * 2;         // bf16 [50000][256]
    char* base = (char*)d_ws;
    size_t off = 0;
    auto take = [&](size_t bytes) { char* p = base + off; off = al256(off + bytes); return p; };

    ushort* h1b  = (ushort*)take(NM256);            // layer1 GEMM out (bf16); reused as layer2 gb
    ushort* xb   = (ushort*)take(NM256);            // RNE bf16 of x
    ushort* hb   = (ushort*)take(NM256);            // RNE bf16 of relu(out_h)
    ushort* w1th = (ushort*)take(256 * 256 * 2);
    ushort* w1tl = (ushort*)take(256 * 256 * 2);
    ushort* w2th = (ushort*)take(256 * 128 * 2);
    ushort* w2tl = (ushort*)take(256 * 128 * 2);
    float*  w1s  = (float*)take(256 * 4);
    float*  w1d  = (float*)take(256 * 4);
    float*  w2s  = (float*)take(256 * 4);
    float*  w2d  = (float*)take(256 * 4);
    float*  a1s  = (float*)take(N_NODES * 4);
    float*  a1d  = (float*)take(N_NODES * 4);
    float*  a2s  = (float*)take(N_NODES * 4);
    float*  a2d  = (float*)take(N_NODES * 4);
    int*    deg  = (int*)take(N_NODES * 4);
    int*    offs = (int*)take((N_NODES + 4) * 4);
    int*    curs = (int*)take((N_NODES + 4) * 4);
    int*    bsum = (int*)take(1024);
    int*    esrc = (int*)take((size_t)ETOT * 4);
    (void)ws_size;

    hipMemsetAsync(deg, 0, N_NODES * sizeof(int), stream);

    int nbE = (ETOT + 255) / 256;
    int nbN = (N_NODES + 255) / 256;
    int nbW = (N_NODES * 64 + 255) / 256;       // one wave per node

    // CSR by dst
    k_deg<<<nbE, 256, 0, stream>>>(ei, deg);
    k_scan1<<<nbN, 256, 0, stream>>>(deg, offs, bsum);
    k_scan2<<<1, 256, 0, stream>>>(bsum, nbN);
    k_scan3<<<nbN, 256, 0, stream>>>(offs, bsum, curs);
    k_scatter<<<nbE, 256, 0, stream>>>(ei, curs, esrc);

    // weight prep: transpose+split, alpha GEMV vectors, x conversion + layer1 alphas
    k_splitT<<<(256 * 256 + 255) / 256, 256, 0, stream>>>(W1, w1th, w1tl, 256, 256);
    k_splitT<<<(256 * 128 + 255) / 256, 256, 0, stream>>>(W2, w2th, w2tl, 256, 128);
    k_wvec<<<256, 256, 0, stream>>>(W1, as1, ad1, W2, as2, ad2, w1s, w1d, w2s, w2d);
    k_prep1<<<nbW, 256, 0, stream>>>(x, w1s, w1d, xb, a1s, a1d);

    dim3 g1((N_NODES + 127) / 128, 2), g2((N_NODES + 127) / 128, 1);

    // ---- layer 1
    k_gemm_mfma<<<g1, 256, 0, stream>>>(xb, w1th, w1tl, h1b, N_NODES, 256);
    k_aggf<256, true, true, true><<<nbW, 256, 0, stream>>>(offs, esrc, a1s, a1d, h1b, b1,
                                                           out_h, hb, w2s, w2d, a2s, a2d);

    // ---- layer 2 (A = hb bf16; gb reuses h1b)
    ushort* gb = h1b;
    k_gemm_mfma<<<g2, 256, 0, stream>>>(hb, w2th, w2tl, gb, N_NODES, 128);
    k_aggf<128, false, false, false><<<nbW, 256, 0, stream>>>(offs, esrc, a2s, a2d, gb, b2,
                                                              out_x2, nullptr, nullptr, nullptr,
                                                              nullptr, nullptr);
}

// Round 18
// 289.497 us; speedup vs baseline: 1.3570x; 1.3570x over previous
//
#include <hip/hip_runtime.h>
#include <hip/hip_bf16.h>

#define N_NODES 50000
#define E0      800000
#define ETOT    850000

typedef __bf16 bf16x8 __attribute__((ext_vector_type(8)));
typedef float  f32x4  __attribute__((ext_vector_type(4)));
typedef ushort u16x8  __attribute__((ext_vector_type(8)));
union B8 { u16x8 u; bf16x8 b; };

static __device__ __forceinline__ float b2f(ushort u) {
    union { uint u; float f; } x; x.u = ((uint)u) << 16; return x.f;
}
static __device__ __forceinline__ ushort f2bf(float f) {
    uint u = __builtin_bit_cast(uint, f);
    uint r = (u + 0x7FFFu + ((u >> 16) & 1u)) >> 16;   // RNE; inputs finite
    return (ushort)r;
}

// ---------------- CSR build ----------------

__global__ __launch_bounds__(256) void k_deg(const int* __restrict__ ei, int* __restrict__ deg) {
    int e = blockIdx.x * 256 + threadIdx.x;
    if (e >= ETOT) return;
    int dst = (e < E0) ? ei[E0 + e] : (e - E0);
    atomicAdd(&deg[dst], 1);
}

__global__ __launch_bounds__(256) void k_scan1(const int* __restrict__ deg, int* __restrict__ offs,
                                               int* __restrict__ bsum) {
    __shared__ int buf[256];
    int tid = threadIdx.x;
    int i = blockIdx.x * 256 + tid;
    int v = (i < N_NODES) ? deg[i] : 0;
    buf[tid] = v;
    __syncthreads();
    for (int off = 1; off < 256; off <<= 1) {
        int t = (tid >= off) ? buf[tid - off] : 0;
        __syncthreads();
        buf[tid] += t;
        __syncthreads();
    }
    if (i < N_NODES) offs[i + 1] = buf[tid];
    if (tid == 255) bsum[blockIdx.x] = buf[255];
}

__global__ __launch_bounds__(256) void k_scan2(int* __restrict__ bsum, int nb) {
    __shared__ int buf[256];
    int tid = threadIdx.x;
    int v = (tid < nb) ? bsum[tid] : 0;
    buf[tid] = v;
    __syncthreads();
    for (int off = 1; off < 256; off <<= 1) {
        int t = (tid >= off) ? buf[tid - off] : 0;
        __syncthreads();
        buf[tid] += t;
        __syncthreads();
    }
    if (tid < nb) bsum[tid] = buf[tid] - v;
}

// also fills cursor (saves a kernel)
__global__ __launch_bounds__(256) void k_scan3(int* __restrict__ offs, const int* __restrict__ bsum,
                                               int* __restrict__ cursor) {
    int tid = threadIdx.x;
    int i = blockIdx.x * 256 + tid;
    if (i < N_NODES) {
        int v = offs[i + 1] + bsum[blockIdx.x];
        offs[i + 1] = v;
        cursor[i + 1] = v;
    }
    if (i == 0) { offs[0] = 0; cursor[0] = 0; }
}

__global__ __launch_bounds__(256) void k_scatter(const int* __restrict__ ei, int* __restrict__ cursor,
                                                 int* __restrict__ esrc) {
    int e = blockIdx.x * 256 + threadIdx.x;
    if (e >= ETOT) return;
    int src, dst;
    if (e < E0) { src = ei[e]; dst = ei[E0 + e]; }
    else        { src = e - E0; dst = src; }
    int pos = atomicAdd(&cursor[dst], 1);
    esrc[pos] = src;
}

// W [K][N] fp32 -> Wt_hi/Wt_lo [N][K] bf16 (tiny)
__global__ __launch_bounds__(256) void k_splitT(const float* __restrict__ W, ushort* __restrict__ th,
                                                ushort* __restrict__ tl, int K, int N) {
    int i = blockIdx.x * 256 + threadIdx.x;
    if (i >= K * N) return;
    int n = i / K, k = i - n * K;
    float v = W[(size_t)k * N + n];
    ushort h = f2bf(v);
    th[(size_t)n * K + k] = h;
    tl[(size_t)n * K + k] = f2bf(v - b2f(h));
}

// w1s = W1 @ a_src1, w1d = W1 @ a_dst1, w2s = W2 @ a_src2, w2d = W2 @ a_dst2
__global__ __launch_bounds__(256) void k_wvec(const float* __restrict__ W1, const float* __restrict__ s1v,
                                              const float* __restrict__ d1v, const float* __restrict__ W2,
                                              const float* __restrict__ s2v, const float* __restrict__ d2v,
                                              float* __restrict__ w1s, float* __restrict__ w1d,
                                              float* __restrict__ w2s, float* __restrict__ w2d) {
    int gw = (blockIdx.x * 256 + threadIdx.x) >> 6;
    int lane = threadIdx.x & 63;
    int vec = gw >> 8, kk = gw & 255;
    float a = 0.f;
    if (vec == 0)      { for (int n = lane; n < 256; n += 64) a += W1[(size_t)kk * 256 + n] * s1v[n]; }
    else if (vec == 1) { for (int n = lane; n < 256; n += 64) a += W1[(size_t)kk * 256 + n] * d1v[n]; }
    else if (vec == 2) { for (int n = lane; n < 128; n += 64) a += W2[(size_t)kk * 128 + n] * s2v[n]; }
    else               { for (int n = lane; n < 128; n += 64) a += W2[(size_t)kk * 128 + n] * d2v[n]; }
    for (int o = 32; o; o >>= 1) a += __shfl_down(a, o);
    if (lane == 0) {
        if (vec == 0) w1s[kk] = a;
        else if (vec == 1) w1d[kk] = a;
        else if (vec == 2) w2s[kk] = a;
        else w2d[kk] = a;
    }
}

// one wave per row: x -> bf16 xb, plus layer1 alphas as1 = x.w1s, ad1 = x.w1d
__global__ __launch_bounds__(256) void k_prep1(const float* __restrict__ x, const float* __restrict__ w1s,
                                               const float* __restrict__ w1d, ushort* __restrict__ xb,
                                               float* __restrict__ as1, float* __restrict__ ad1) {
    int gw = (blockIdx.x * 256 + threadIdx.x) >> 6;
    int lane = threadIdx.x & 63;
    if (gw >= N_NODES) return;
    float4 v = *(const float4*)(x + (size_t)gw * 256 + lane * 4);
    ushort4 h;
    h.x = f2bf(v.x); h.y = f2bf(v.y); h.z = f2bf(v.z); h.w = f2bf(v.w);
    *(ushort4*)(xb + (size_t)gw * 256 + lane * 4) = h;
    float4 cs = *(const float4*)(w1s + lane * 4);
    float4 cd = *(const float4*)(w1d + lane * 4);
    float s = v.x * cs.x + v.y * cs.y + v.z * cs.z + v.w * cs.w;
    float d = v.x * cd.x + v.y * cd.y + v.z * cd.z + v.w * cd.w;
    for (int o = 32; o; o >>= 1) { s += __shfl_down(s, o); d += __shfl_down(d, o); }
    if (lane == 0) { as1[gw] = s; ad1[gw] = d; }
}

// ---------------- MFMA GEMM: A bf16 (pre-rounded), B hi/lo LDS dbuf ----------------
// [R13 config — best measured; frozen]

__global__ __launch_bounds__(256, 2) void k_gemm_mfma(const ushort* __restrict__ Ab,
                                                      const ushort* __restrict__ Bth,
                                                      const ushort* __restrict__ Btl,
                                                      ushort* __restrict__ Cb, int M, int Nn) {
    constexpr int K = 256;
    __shared__ ushort lds[2][2][8][128][8];      // 64 KB
    int tid = threadIdx.x;
    int wid = tid >> 6, lane = tid & 63;
    int wr = wid >> 1, wc = wid & 1;
    int bm = blockIdx.x * 128, bn = blockIdx.y * 128;
    int lr = lane & 15, lg = lane >> 4;

    int sa = tid >> 7, scol = tid & 127;
    const ushort* sb = (sa ? Btl : Bth) + (size_t)(bn + scol) * K;

    const ushort* Ap[4];
#pragma unroll
    for (int m = 0; m < 4; ++m) {
        int row = bm + wr * 64 + m * 16 + lr;
        if (row >= M) row = M - 1;
        Ap[m] = Ab + (size_t)row * K + lg * 8;
    }

    f32x4 acc[4][4] = {};
    u16x8 sv[8];
    bf16x8 aH[2][4];

#pragma unroll
    for (int c = 0; c < 8; ++c) sv[c] = *(const u16x8*)(sb + c * 8);
#pragma unroll
    for (int m = 0; m < 4; ++m) {
        aH[0][m] = *(const bf16x8*)(Ap[m]);
        aH[1][m] = *(const bf16x8*)(Ap[m] + 32);
    }
#pragma unroll
    for (int c = 0; c < 8; ++c) *(u16x8*)&lds[0][sa][c][scol][0] = sv[c];
    __syncthreads();

#pragma unroll
    for (int s = 0; s < 8; ++s) {
        const int w = s >> 1, buf = w & 1, kk = s & 1;
        if (kk == 0 && w < 3) {
#pragma unroll
            for (int c = 0; c < 8; ++c) sv[c] = *(const u16x8*)(sb + (w + 1) * 64 + c * 8);
        }
        bf16x8 bh[4], bl[4];
#pragma unroll
        for (int n = 0; n < 4; ++n) {
            int col = wc * 64 + n * 16 + lr;
            B8 th, tl2;
            th.u = *(const u16x8*)&lds[buf][0][kk * 4 + lg][col][0];
            tl2.u = *(const u16x8*)&lds[buf][1][kk * 4 + lg][col][0];
            bh[n] = th.b; bl[n] = tl2.b;
        }
        bf16x8 ah[4];
#pragma unroll
        for (int m = 0; m < 4; ++m) ah[m] = aH[s & 1][m];
        if (s < 6) {
#pragma unroll
            for (int m = 0; m < 4; ++m) aH[s & 1][m] = *(const bf16x8*)(Ap[m] + (s + 2) * 32);
        }
#pragma unroll
        for (int m = 0; m < 4; ++m)
#pragma unroll
            for (int n = 0; n < 4; ++n) {
                acc[m][n] = __builtin_amdgcn_mfma_f32_16x16x32_bf16(ah[m], bh[n], acc[m][n], 0, 0, 0);
                acc[m][n] = __builtin_amdgcn_mfma_f32_16x16x32_bf16(ah[m], bl[n], acc[m][n], 0, 0, 0);
            }
        if (kk == 1 && w < 3) {
#pragma unroll
            for (int c = 0; c < 8; ++c) *(u16x8*)&lds[buf ^ 1][sa][c][scol][0] = sv[c];
            __syncthreads();
        }
    }
    // C/D layout: col = lane&15, row = (lane>>4)*4 + reg   [m89-verified]
#pragma unroll
    for (int m = 0; m < 4; ++m)
#pragma unroll
        for (int r = 0; r < 4; ++r) {
            int row = bm + wr * 64 + m * 16 + lg * 4 + r;
            if (row < M) {
#pragma unroll
                for (int n = 0; n < 4; ++n) {
                    int col = bn + wc * 64 + n * 16 + lr;
                    Cb[(size_t)row * Nn + col] = f2bf(acc[m][n][r]);
                }
            }
        }
}

// ---- fused online-softmax aggregation, 8-edge unroll (single buffer, R15) ----
// A2: epilogue computes layer2 alphas from registers; WB: bf16 copy of result.
template <int F, bool RELU, bool WB, bool A2>
__global__ __launch_bounds__(256) void k_aggf(const int* __restrict__ offs, const int* __restrict__ esrc,
                                              const float* __restrict__ as, const float* __restrict__ ad,
                                              const ushort* __restrict__ H, const float* __restrict__ bias,
                                              float* __restrict__ out, ushort* __restrict__ hb,
                                              const float* __restrict__ w2s, const float* __restrict__ w2d,
                                              float* __restrict__ as2, float* __restrict__ ad2) {
    constexpr int V = F / 64;
    constexpr float THR = 8.f;
    int gw = (blockIdx.x * 256 + threadIdx.x) >> 6;
    int lane = threadIdx.x & 63;
    if (gw >= N_NODES) return;
    int s0 = offs[gw], s1 = offs[gw + 1];
    float adi = ad[gw];
    float m = -1e30f, ssum = 0.f;
    float acc[V] = {};
    int k = s0;
    for (; k + 7 < s1; k += 8) {
        int rr[8];
#pragma unroll
        for (int q = 0; q < 8; ++q) rr[q] = esrc[k + q];
        float ev[8];
#pragma unroll
        for (int q = 0; q < 8; ++q) ev[q] = as[rr[q]];
        float rows[8][V];
#pragma unroll
        for (int q = 0; q < 8; ++q) {
            if constexpr (V == 4) {
                ushort4 v = *(const ushort4*)(H + (size_t)rr[q] * F + lane * 4);
                rows[q][0] = b2f(v.x); rows[q][1] = b2f(v.y); rows[q][2] = b2f(v.z); rows[q][3] = b2f(v.w);
            } else {
                ushort2 v = *(const ushort2*)(H + (size_t)rr[q] * F + lane * 2);
                rows[q][0] = b2f(v.x); rows[q][1] = b2f(v.y);
            }
        }
        float em = -1e30f;
#pragma unroll
        for (int q = 0; q < 8; ++q) {
            float e = ev[q] + adi;
            e = e > 0.f ? e : 0.2f * e;
            ev[q] = e;
            em = fmaxf(em, e);
        }
        if (em > m + THR) {                    // wave-uniform
            float sc = __expf(m - em);
            ssum *= sc;
#pragma unroll
            for (int j = 0; j < V; ++j) acc[j] *= sc;
            m = em;
        }
        float w[8];
#pragma unroll
        for (int q = 0; q < 8; ++q) w[q] = __expf(ev[q] - m);
#pragma unroll
        for (int q = 0; q < 8; ++q) ssum += w[q];
#pragma unroll
        for (int j = 0; j < V; ++j) {
            float a = acc[j];
#pragma unroll
            for (int q = 0; q < 8; ++q) a += w[q] * rows[q][j];
            acc[j] = a;
        }
    }
    for (; k + 3 < s1; k += 4) {
        int rr[4];
#pragma unroll
        for (int q = 0; q < 4; ++q) rr[q] = esrc[k + q];
        float ev[4];
#pragma unroll
        for (int q = 0; q < 4; ++q) ev[q] = as[rr[q]];
        float rows[4][V];
#pragma unroll
        for (int q = 0; q < 4; ++q) {
            if constexpr (V == 4) {
                ushort4 v = *(const ushort4*)(H + (size_t)rr[q] * F + lane * 4);
                rows[q][0] = b2f(v.x); rows[q][1] = b2f(v.y); rows[q][2] = b2f(v.z); rows[q][3] = b2f(v.w);
            } else {
                ushort2 v = *(const ushort2*)(H + (size_t)rr[q] * F + lane * 2);
                rows[q][0] = b2f(v.x); rows[q][1] = b2f(v.y);
            }
        }
        float em = -1e30f;
#pragma unroll
        for (int q = 0; q < 4; ++q) {
            float e = ev[q] + adi;
            e = e > 0.f ? e : 0.2f * e;
            ev[q] = e;
            em = fmaxf(em, e);
        }
        if (em > m + THR) {
            float sc = __expf(m - em);
            ssum *= sc;
#pragma unroll
            for (int j = 0; j < V; ++j) acc[j] *= sc;
            m = em;
        }
        float w[4];
#pragma unroll
        for (int q = 0; q < 4; ++q) w[q] = __expf(ev[q] - m);
#pragma unroll
        for (int q = 0; q < 4; ++q) ssum += w[q];
#pragma unroll
        for (int j = 0; j < V; ++j) {
            float a = acc[j];
#pragma unroll
            for (int q = 0; q < 4; ++q) a += w[q] * rows[q][j];
            acc[j] = a;
        }
    }
    for (; k < s1; ++k) {
        int r0 = esrc[k];
        float row0[V];
        if constexpr (V == 4) {
            ushort4 v0 = *(const ushort4*)(H + (size_t)r0 * F + lane * 4);
            row0[0] = b2f(v0.x); row0[1] = b2f(v0.y); row0[2] = b2f(v0.z); row0[3] = b2f(v0.w);
        } else {
            ushort2 v0 = *(const ushort2*)(H + (size_t)r0 * F + lane * 2);
            row0[0] = b2f(v0.x); row0[1] = b2f(v0.y);
        }
        float e0 = as[r0] + adi; e0 = e0 > 0.f ? e0 : 0.2f * e0;
        if (e0 > m + THR) {
            float sc = __expf(m - e0);
            ssum *= sc;
#pragma unroll
            for (int j = 0; j < V; ++j) acc[j] *= sc;
            m = e0;
        }
        float w0 = __expf(e0 - m);
        ssum += w0;
#pragma unroll
        for (int j = 0; j < V; ++j) acc[j] += w0 * row0[j];
    }
    float inv = 1.f / ssum;
    float r[V];
#pragma unroll
    for (int j = 0; j < V; ++j) {
        r[j] = acc[j] * inv + bias[lane * V + j];
        if (RELU) r[j] = fmaxf(r[j], 0.f);
    }
    if (V == 4) *(float4*)(out + (size_t)gw * F + lane * 4) = make_float4(r[0], r[1], r[2], r[3]);
    else        *(float2*)(out + (size_t)gw * F + lane * 2) = make_float2(r[0], r[1]);
    if constexpr (WB && V == 4) {
        ushort4 h4;
        h4.x = f2bf(r[0]); h4.y = f2bf(r[1]); h4.z = f2bf(r[2]); h4.w = f2bf(r[3]);
        *(ushort4*)(hb + (size_t)gw * F + lane * 4) = h4;
    }
    if constexpr (A2 && V == 4) {
        float4 cs = *(const float4*)(w2s + lane * 4);
        float4 cd = *(const float4*)(w2d + lane * 4);
        float s2 = r[0] * cs.x + r[1] * cs.y + r[2] * cs.z + r[3] * cs.w;
        float d2 = r[0] * cd.x + r[1] * cd.y + r[2] * cd.z + r[3] * cd.w;
        for (int o = 32; o; o >>= 1) { s2 += __shfl_down(s2, o); d2 += __shfl_down(d2, o); }
        if (lane == 0) { as2[gw] = s2; ad2[gw] = d2; }
    }
}

// ---------------- launch ----------------

static inline size_t al256(size_t x) { return (x + 255) & ~(size_t)255; }

extern "C" void kernel_launch(void* const* d_in, const int* in_sizes, int n_in,
                              void* d_out, int out_size, void* d_ws, size_t ws_size,
                              hipStream_t stream) {
    const float* x   = (const float*)d_in[0];
    const int*   ei  = (const int*)d_in[1];
    const float* W1  = (const float*)d_in[2];
    const float* as1 = (const float*)d_in[3];
    const float* ad1 = (const float*)d_in[4];
    const float* b1  = (const float*)d_in[5];
    const float* W2  = (const float*)d_in[6];
    const float* as2 = (const float*)d_in[7];
    const float* ad2 = (const float*)d_in[8];
    const float* b2  = (const float*)d_in[9];

    float* out_x2 = (float*)d_out;                          // [50000,128]
    float* out_h  = (float*)d_out + (size_t)N_NODES * 128;  // [50000,256] fp32

    const size_t NM256 = (size_t)N_NODES * 256 * 2;         // bf16 [50000][256]
    char* base = (char*)d_ws;
    size_t off = 0;
    auto take = [&](size_t bytes) { char* p = base + off; off = al256(off + bytes); return p; };

    ushort* h1b  = (ushort*)take(NM256);            // layer1 GEMM out (bf16); reused as layer2 gb
    ushort* xb   = (ushort*)take(NM256);            // RNE bf16 of x
    ushort* hb   = (ushort*)take(NM256);            // RNE bf16 of relu(out_h)
    ushort* w1th = (ushort*)take(256 * 256 * 2);
    ushort* w1tl = (ushort*)take(256 * 256 * 2);
    ushort* w2th = (ushort*)take(256 * 128 * 2);
    ushort* w2tl = (ushort*)take(256 * 128 * 2);
    float*  w1s  = (float*)take(256 * 4);
    float*  w1d  = (float*)take(256 * 4);
    float*  w2s  = (float*)take(256 * 4);
    float*  w2d  = (float*)take(256 * 4);
    float*  a1s  = (float*)take(N_NODES * 4);
    float*  a1d  = (float*)take(N_NODES * 4);
    float*  a2s  = (float*)take(N_NODES * 4);
    float*  a2d  = (float*)take(N_NODES * 4);
    int*    deg  = (int*)take(N_NODES * 4);
    int*    offs = (int*)take((N_NODES + 4) * 4);
    int*    curs = (int*)take((N_NODES + 4) * 4);
    int*    bsum = (int*)take(1024);
    int*    esrc = (int*)take((size_t)ETOT * 4);
    (void)ws_size;

    hipMemsetAsync(deg, 0, N_NODES * sizeof(int), stream);

    int nbE = (ETOT + 255) / 256;
    int nbN = (N_NODES + 255) / 256;
    int nbW = (N_NODES * 64 + 255) / 256;       // one wave per node

    // CSR by dst
    k_deg<<<nbE, 256, 0, stream>>>(ei, deg);
    k_scan1<<<nbN, 256, 0, stream>>>(deg, offs, bsum);
    k_scan2<<<1, 256, 0, stream>>>(bsum, nbN);
    k_scan3<<<nbN, 256, 0, stream>>>(offs, bsum, curs);
    k_scatter<<<nbE, 256, 0, stream>>>(ei, curs, esrc);

    // weight prep: transpose+split, alpha GEMV vectors, x conversion + layer1 alphas
    k_splitT<<<(256 * 256 + 255) / 256, 256, 0, stream>>>(W1, w1th, w1tl, 256, 256);
    k_splitT<<<(256 * 128 + 255) / 256, 256, 0, stream>>>(W2, w2th, w2tl, 256, 128);
    k_wvec<<<256, 256, 0, stream>>>(W1, as1, ad1, W2, as2, ad2, w1s, w1d, w2s, w2d);
    k_prep1<<<nbW, 256, 0, stream>>>(x, w1s, w1d, xb, a1s, a1d);

    dim3 g1((N_NODES + 127) / 128, 2), g2((N_NODES + 127) / 128, 1);

    // ---- layer 1
    k_gemm_mfma<<<g1, 256, 0, stream>>>(xb, w1th, w1tl, h1b, N_NODES, 256);
    k_aggf<256, true, true, true><<<nbW, 256, 0, stream>>>(offs, esrc, a1s, a1d, h1b, b1,
                                                           out_h, hb, w2s, w2d, a2s, a2d);

    // ---- layer 2 (A = hb bf16; gb reuses h1b)
    ushort* gb = h1b;
    k_gemm_mfma<<<g2, 256, 0, stream>>>(hb, w2th, w2tl, gb, N_NODES, 128);
    k_aggf<128, false, false, false><<<nbW, 256, 0, stream>>>(offs, esrc, a2s, a2d, gb, b2,
                                                              out_x2, nullptr, nullptr, nullptr,
                                                              nullptr, nullptr);
}

// Round 19
// 272.668 us; speedup vs baseline: 1.4407x; 1.0617x over previous
//
#include <hip/hip_runtime.h>
#include <hip/hip_bf16.h>

#define N_NODES 50000
#define E0      800000
#define ETOT    850000

typedef __bf16 bf16x8 __attribute__((ext_vector_type(8)));
typedef float  f32x4  __attribute__((ext_vector_type(4)));
typedef ushort u16x8  __attribute__((ext_vector_type(8)));
union B8 { u16x8 u; bf16x8 b; };

static __device__ __forceinline__ float b2f(ushort u) {
    union { uint u; float f; } x; x.u = ((uint)u) << 16; return x.f;
}
static __device__ __forceinline__ ushort f2bf(float f) {
    uint u = __builtin_bit_cast(uint, f);
    uint r = (u + 0x7FFFu + ((u >> 16) & 1u)) >> 16;   // RNE; inputs finite
    return (ushort)r;
}

// async global->LDS, 16B per lane (linear LDS: base + lane*16)
static __device__ __forceinline__ void gload16(const ushort* g, ushort* l) {
    __builtin_amdgcn_global_load_lds((const __attribute__((address_space(1))) unsigned int*)g,
                                     (__attribute__((address_space(3))) unsigned int*)l, 16, 0, 0);
}

// ---------------- CSR build ----------------

__global__ __launch_bounds__(256) void k_deg(const int* __restrict__ ei, int* __restrict__ deg) {
    int e = blockIdx.x * 256 + threadIdx.x;
    if (e >= ETOT) return;
    int dst = (e < E0) ? ei[E0 + e] : (e - E0);
    atomicAdd(&deg[dst], 1);
}

__global__ __launch_bounds__(256) void k_scan1(const int* __restrict__ deg, int* __restrict__ offs,
                                               int* __restrict__ bsum) {
    __shared__ int buf[256];
    int tid = threadIdx.x;
    int i = blockIdx.x * 256 + tid;
    int v = (i < N_NODES) ? deg[i] : 0;
    buf[tid] = v;
    __syncthreads();
    for (int off = 1; off < 256; off <<= 1) {
        int t = (tid >= off) ? buf[tid - off] : 0;
        __syncthreads();
        buf[tid] += t;
        __syncthreads();
    }
    if (i < N_NODES) offs[i + 1] = buf[tid];
    if (tid == 255) bsum[blockIdx.x] = buf[255];
}

__global__ __launch_bounds__(256) void k_scan2(int* __restrict__ bsum, int nb) {
    __shared__ int buf[256];
    int tid = threadIdx.x;
    int v = (tid < nb) ? bsum[tid] : 0;
    buf[tid] = v;
    __syncthreads();
    for (int off = 1; off < 256; off <<= 1) {
        int t = (tid >= off) ? buf[tid - off] : 0;
        __syncthreads();
        buf[tid] += t;
        __syncthreads();
    }
    if (tid < nb) bsum[tid] = buf[tid] - v;
}

// also fills cursor (saves a kernel)
__global__ __launch_bounds__(256) void k_scan3(int* __restrict__ offs, const int* __restrict__ bsum,
                                               int* __restrict__ cursor) {
    int tid = threadIdx.x;
    int i = blockIdx.x * 256 + tid;
    if (i < N_NODES) {
        int v = offs[i + 1] + bsum[blockIdx.x];
        offs[i + 1] = v;
        cursor[i + 1] = v;
    }
    if (i == 0) { offs[0] = 0; cursor[0] = 0; }
}

__global__ __launch_bounds__(256) void k_scatter(const int* __restrict__ ei, int* __restrict__ cursor,
                                                 int* __restrict__ esrc) {
    int e = blockIdx.x * 256 + threadIdx.x;
    if (e >= ETOT) return;
    int src, dst;
    if (e < E0) { src = ei[e]; dst = ei[E0 + e]; }
    else        { src = e - E0; dst = src; }
    int pos = atomicAdd(&cursor[dst], 1);
    esrc[pos] = src;
}

// W [K][N] fp32 -> Wt_hi/Wt_lo [N][K] bf16 (tiny)
__global__ __launch_bounds__(256) void k_splitT(const float* __restrict__ W, ushort* __restrict__ th,
                                                ushort* __restrict__ tl, int K, int N) {
    int i = blockIdx.x * 256 + threadIdx.x;
    if (i >= K * N) return;
    int n = i / K, k = i - n * K;
    float v = W[(size_t)k * N + n];
    ushort h = f2bf(v);
    th[(size_t)n * K + k] = h;
    tl[(size_t)n * K + k] = f2bf(v - b2f(h));
}

// w1s = W1 @ a_src1, w1d = W1 @ a_dst1, w2s = W2 @ a_src2, w2d = W2 @ a_dst2
__global__ __launch_bounds__(256) void k_wvec(const float* __restrict__ W1, const float* __restrict__ s1v,
                                              const float* __restrict__ d1v, const float* __restrict__ W2,
                                              const float* __restrict__ s2v, const float* __restrict__ d2v,
                                              float* __restrict__ w1s, float* __restrict__ w1d,
                                              float* __restrict__ w2s, float* __restrict__ w2d) {
    int gw = (blockIdx.x * 256 + threadIdx.x) >> 6;
    int lane = threadIdx.x & 63;
    int vec = gw >> 8, kk = gw & 255;
    float a = 0.f;
    if (vec == 0)      { for (int n = lane; n < 256; n += 64) a += W1[(size_t)kk * 256 + n] * s1v[n]; }
    else if (vec == 1) { for (int n = lane; n < 256; n += 64) a += W1[(size_t)kk * 256 + n] * d1v[n]; }
    else if (vec == 2) { for (int n = lane; n < 128; n += 64) a += W2[(size_t)kk * 128 + n] * s2v[n]; }
    else               { for (int n = lane; n < 128; n += 64) a += W2[(size_t)kk * 128 + n] * d2v[n]; }
    for (int o = 32; o; o >>= 1) a += __shfl_down(a, o);
    if (lane == 0) {
        if (vec == 0) w1s[kk] = a;
        else if (vec == 1) w1d[kk] = a;
        else if (vec == 2) w2s[kk] = a;
        else w2d[kk] = a;
    }
}

// one wave per row: x -> bf16 xb, plus layer1 alphas as1 = x.w1s, ad1 = x.w1d
__global__ __launch_bounds__(256) void k_prep1(const float* __restrict__ x, const float* __restrict__ w1s,
                                               const float* __restrict__ w1d, ushort* __restrict__ xb,
                                               float* __restrict__ as1, float* __restrict__ ad1) {
    int gw = (blockIdx.x * 256 + threadIdx.x) >> 6;
    int lane = threadIdx.x & 63;
    if (gw >= N_NODES) return;
    float4 v = *(const float4*)(x + (size_t)gw * 256 + lane * 4);
    ushort4 h;
    h.x = f2bf(v.x); h.y = f2bf(v.y); h.z = f2bf(v.z); h.w = f2bf(v.w);
    *(ushort4*)(xb + (size_t)gw * 256 + lane * 4) = h;
    float4 cs = *(const float4*)(w1s + lane * 4);
    float4 cd = *(const float4*)(w1d + lane * 4);
    float s = v.x * cs.x + v.y * cs.y + v.z * cs.z + v.w * cs.w;
    float d = v.x * cd.x + v.y * cd.y + v.z * cd.z + v.w * cd.w;
    for (int o = 32; o; o >>= 1) { s += __shfl_down(s, o); d += __shfl_down(d, o); }
    if (lane == 0) { as1[gw] = s; ad1[gw] = d; }
}

// ---------------- MFMA GEMM: m97-style async LDS staging ----------------
// Cb[M][Nn](bf16) = Ab[M][K=256](bf16) @ (Bth+Btl)[Nn][K]^T
// 128x128 tile, 4 waves (2x2), BK=32, 8 steps, double-buffered 48KB LDS.
// A + Bh + Bl staged via global_load_lds(16B) -> no VGPR round trip.
// A rows beyond M read into ws pad (results discarded). 2 MFMA streams.

__global__ __launch_bounds__(256, 3) void k_gemm_mfma(const ushort* __restrict__ Ab,
                                                      const ushort* __restrict__ Bth,
                                                      const ushort* __restrict__ Btl,
                                                      ushort* __restrict__ Cb, int M, int Nn) {
    constexpr int K = 256;
    __shared__ ushort ldsA[2][128][32];          // 16 KB
    __shared__ ushort ldsB[2][2][128][32];       // 32 KB  [buf][hi/lo][col][k]
    int tid = threadIdx.x;
    int wid = tid >> 6, lane = tid & 63;
    int wr = wid >> 1, wc = wid & 1;
    int bm = blockIdx.x * 128, bn = blockIdx.y * 128;
    int lr = lane & 15, lg = lane >> 4;

    // staging: thread t covers (row = t/4 + 64i, k = (t%4)*8), i = 0,1
    int srow = tid >> 2, sk = (tid & 3) << 3;
    const ushort* ga0  = Ab  + (size_t)(bm + srow) * K + sk;
    const ushort* ga1  = Ab  + (size_t)(bm + srow + 64) * K + sk;
    const ushort* gbh0 = Bth + (size_t)(bn + srow) * K + sk;
    const ushort* gbh1 = Bth + (size_t)(bn + srow + 64) * K + sk;
    const ushort* gbl0 = Btl + (size_t)(bn + srow) * K + sk;
    const ushort* gbl1 = Btl + (size_t)(bn + srow + 64) * K + sk;

#define STAGE(B, KT) do {                                   \
    gload16(ga0  + (KT), &ldsA[B][srow][sk]);               \
    gload16(ga1  + (KT), &ldsA[B][srow + 64][sk]);          \
    gload16(gbh0 + (KT), &ldsB[B][0][srow][sk]);            \
    gload16(gbh1 + (KT), &ldsB[B][0][srow + 64][sk]);       \
    gload16(gbl0 + (KT), &ldsB[B][1][srow][sk]);            \
    gload16(gbl1 + (KT), &ldsB[B][1][srow + 64][sk]);       \
} while (0)

    f32x4 acc[4][4] = {};

    STAGE(0, 0);
    __syncthreads();

#pragma unroll
    for (int s = 0; s < 8; ++s) {
        const int buf = s & 1;
        if (s < 7) STAGE(buf ^ 1, (s + 1) * 32);
        bf16x8 ah[4], bh[4], bl[4];
#pragma unroll
        for (int m = 0; m < 4; ++m)
            ah[m] = *(const bf16x8*)&ldsA[buf][wr * 64 + m * 16 + lr][lg * 8];
#pragma unroll
        for (int n = 0; n < 4; ++n) {
            bh[n] = *(const bf16x8*)&ldsB[buf][0][wc * 64 + n * 16 + lr][lg * 8];
            bl[n] = *(const bf16x8*)&ldsB[buf][1][wc * 64 + n * 16 + lr][lg * 8];
        }
#pragma unroll
        for (int m = 0; m < 4; ++m)
#pragma unroll
            for (int n = 0; n < 4; ++n) {
                acc[m][n] = __builtin_amdgcn_mfma_f32_16x16x32_bf16(ah[m], bh[n], acc[m][n], 0, 0, 0);
                acc[m][n] = __builtin_amdgcn_mfma_f32_16x16x32_bf16(ah[m], bl[n], acc[m][n], 0, 0, 0);
            }
        __syncthreads();
    }
#undef STAGE
    // C/D layout: col = lane&15, row = (lane>>4)*4 + reg   [m89-verified]
#pragma unroll
    for (int m = 0; m < 4; ++m)
#pragma unroll
        for (int r = 0; r < 4; ++r) {
            int row = bm + wr * 64 + m * 16 + lg * 4 + r;
            if (row < M) {
#pragma unroll
                for (int n = 0; n < 4; ++n) {
                    int col = bn + wc * 64 + n * 16 + lr;
                    Cb[(size_t)row * Nn + col] = f2bf(acc[m][n][r]);
                }
            }
        }
}

// ---- fused online-softmax aggregation, 8-edge unroll (single buffer, R15) ----
// A2: epilogue computes layer2 alphas from registers; WB: bf16 copy of result.
template <int F, bool RELU, bool WB, bool A2>
__global__ __launch_bounds__(256) void k_aggf(const int* __restrict__ offs, const int* __restrict__ esrc,
                                              const float* __restrict__ as, const float* __restrict__ ad,
                                              const ushort* __restrict__ H, const float* __restrict__ bias,
                                              float* __restrict__ out, ushort* __restrict__ hb,
                                              const float* __restrict__ w2s, const float* __restrict__ w2d,
                                              float* __restrict__ as2, float* __restrict__ ad2) {
    constexpr int V = F / 64;
    constexpr float THR = 8.f;
    int gw = (blockIdx.x * 256 + threadIdx.x) >> 6;
    int lane = threadIdx.x & 63;
    if (gw >= N_NODES) return;
    int s0 = offs[gw], s1 = offs[gw + 1];
    float adi = ad[gw];
    float m = -1e30f, ssum = 0.f;
    float acc[V] = {};
    int k = s0;
    for (; k + 7 < s1; k += 8) {
        int rr[8];
#pragma unroll
        for (int q = 0; q < 8; ++q) rr[q] = esrc[k + q];
        float ev[8];
#pragma unroll
        for (int q = 0; q < 8; ++q) ev[q] = as[rr[q]];
        float rows[8][V];
#pragma unroll
        for (int q = 0; q < 8; ++q) {
            if constexpr (V == 4) {
                ushort4 v = *(const ushort4*)(H + (size_t)rr[q] * F + lane * 4);
                rows[q][0] = b2f(v.x); rows[q][1] = b2f(v.y); rows[q][2] = b2f(v.z); rows[q][3] = b2f(v.w);
            } else {
                ushort2 v = *(const ushort2*)(H + (size_t)rr[q] * F + lane * 2);
                rows[q][0] = b2f(v.x); rows[q][1] = b2f(v.y);
            }
        }
        float em = -1e30f;
#pragma unroll
        for (int q = 0; q < 8; ++q) {
            float e = ev[q] + adi;
            e = e > 0.f ? e : 0.2f * e;
            ev[q] = e;
            em = fmaxf(em, e);
        }
        if (em > m + THR) {                    // wave-uniform
            float sc = __expf(m - em);
            ssum *= sc;
#pragma unroll
            for (int j = 0; j < V; ++j) acc[j] *= sc;
            m = em;
        }
        float w[8];
#pragma unroll
        for (int q = 0; q < 8; ++q) w[q] = __expf(ev[q] - m);
#pragma unroll
        for (int q = 0; q < 8; ++q) ssum += w[q];
#pragma unroll
        for (int j = 0; j < V; ++j) {
            float a = acc[j];
#pragma unroll
            for (int q = 0; q < 8; ++q) a += w[q] * rows[q][j];
            acc[j] = a;
        }
    }
    for (; k + 3 < s1; k += 4) {
        int rr[4];
#pragma unroll
        for (int q = 0; q < 4; ++q) rr[q] = esrc[k + q];
        float ev[4];
#pragma unroll
        for (int q = 0; q < 4; ++q) ev[q] = as[rr[q]];
        float rows[4][V];
#pragma unroll
        for (int q = 0; q < 4; ++q) {
            if constexpr (V == 4) {
                ushort4 v = *(const ushort4*)(H + (size_t)rr[q] * F + lane * 4);
                rows[q][0] = b2f(v.x); rows[q][1] = b2f(v.y); rows[q][2] = b2f(v.z); rows[q][3] = b2f(v.w);
            } else {
                ushort2 v = *(const ushort2*)(H + (size_t)rr[q] * F + lane * 2);
                rows[q][0] = b2f(v.x); rows[q][1] = b2f(v.y);
            }
        }
        float em = -1e30f;
#pragma unroll
        for (int q = 0; q < 4; ++q) {
            float e = ev[q] + adi;
            e = e > 0.f ? e : 0.2f * e;
            ev[q] = e;
            em = fmaxf(em, e);
        }
        if (em > m + THR) {
            float sc = __expf(m - em);
            ssum *= sc;
#pragma unroll
            for (int j = 0; j < V; ++j) acc[j] *= sc;
            m = em;
        }
        float w[4];
#pragma unroll
        for (int q = 0; q < 4; ++q) w[q] = __expf(ev[q] - m);
#pragma unroll
        for (int q = 0; q < 4; ++q) ssum += w[q];
#pragma unroll
        for (int j = 0; j < V; ++j) {
            float a = acc[j];
#pragma unroll
            for (int q = 0; q < 4; ++q) a += w[q] * rows[q][j];
            acc[j] = a;
        }
    }
    for (; k < s1; ++k) {
        int r0 = esrc[k];
        float row0[V];
        if constexpr (V == 4) {
            ushort4 v0 = *(const ushort4*)(H + (size_t)r0 * F + lane * 4);
            row0[0] = b2f(v0.x); row0[1] = b2f(v0.y); row0[2] = b2f(v0.z); row0[3] = b2f(v0.w);
        } else {
            ushort2 v0 = *(const ushort2*)(H + (size_t)r0 * F + lane * 2);
            row0[0] = b2f(v0.x); row0[1] = b2f(v0.y);
        }
        float e0 = as[r0] + adi; e0 = e0 > 0.f ? e0 : 0.2f * e0;
        if (e0 > m + THR) {
            float sc = __expf(m - e0);
            ssum *= sc;
#pragma unroll
            for (int j = 0; j < V; ++j) acc[j] *= sc;
            m = e0;
        }
        float w0 = __expf(e0 - m);
        ssum += w0;
#pragma unroll
        for (int j = 0; j < V; ++j) acc[j] += w0 * row0[j];
    }
    float inv = 1.f / ssum;
    float r[V];
#pragma unroll
    for (int j = 0; j < V; ++j) {
        r[j] = acc[j] * inv + bias[lane * V + j];
        if (RELU) r[j] = fmaxf(r[j], 0.f);
    }
    if (V == 4) *(float4*)(out + (size_t)gw * F + lane * 4) = make_float4(r[0], r[1], r[2], r[3]);
    else        *(float2*)(out + (size_t)gw * F + lane * 2) = make_float2(r[0], r[1]);
    if constexpr (WB && V == 4) {
        ushort4 h4;
        h4.x = f2bf(r[0]); h4.y = f2bf(r[1]); h4.z = f2bf(r[2]); h4.w = f2bf(r[3]);
        *(ushort4*)(hb + (size_t)gw * F + lane * 4) = h4;
    }
    if constexpr (A2 && V == 4) {
        float4 cs = *(const float4*)(w2s + lane * 4);
        float4 cd = *(const float4*)(w2d + lane * 4);
        float s2 = r[0] * cs.x + r[1] * cs.y + r[2] * cs.z + r[3] * cs.w;
        float d2 = r[0] * cd.x + r[1] * cd.y + r[2] * cd.z + r[3] * cd.w;
        for (int o = 32; o; o >>= 1) { s2 += __shfl_down(s2, o); d2 += __shfl_down(d2, o); }
        if (lane == 0) { as2[gw] = s2; ad2[gw] = d2; }
    }
}

// ---------------- launch ----------------

static inline size_t al256(size_t x) { return (x + 255) & ~(size_t)255; }

extern "C" void kernel_launch(void* const* d_in, const int* in_sizes, int n_in,
                              void* d_out, int out_size, void* d_ws, size_t ws_size,
                              hipStream_t stream) {
    const float* x   = (const float*)d_in[0];
    const int*   ei  = (const int*)d_in[1];
    const float* W1  = (const float*)d_in[2];
    const float* as1 = (const float*)d_in[3];
    const float* ad1 = (const float*)d_in[4];
    const float* b1  = (const float*)d_in[5];
    const float* W2  = (const float*)d_in[6];
    const float* as2 = (const float*)d_in[7];
    const float* ad2 = (const float*)d_in[8];
    const float* b2  = (const float*)d_in[9];

    float* out_x2 = (float*)d_out;                          // [50000,128]
    float* out_h  = (float*)d_out + (size_t)N_NODES * 128;  // [50000,256] fp32

    const size_t NM256 = (size_t)N_NODES * 256 * 2;         // bf16 [50000][256]
    const size_t PAD   = (size_t)128 * 256 * 2;             // GEMM A staging pad rows
    char* base = (char*)d_ws;
    size_t off = 0;
    auto take = [&](size_t bytes) { char* p = base + off; off = al256(off + bytes); return p; };

    ushort* h1b  = (ushort*)take(NM256);            // layer1 GEMM out (bf16); reused as layer2 gb
    ushort* xb   = (ushort*)take(NM256 + PAD);      // RNE bf16 of x (+pad for staging reads)
    ushort* hb   = (ushort*)take(NM256 + PAD);      // RNE bf16 of relu(out_h) (+pad)
    ushort* w1th = (ushort*)take(256 * 256 * 2);
    ushort* w1tl = (ushort*)take(256 * 256 * 2);
    ushort* w2th = (ushort*)take(256 * 128 * 2);
    ushort* w2tl = (ushort*)take(256 * 128 * 2);
    float*  w1s  = (float*)take(256 * 4);
    float*  w1d  = (float*)take(256 * 4);
    float*  w2s  = (float*)take(256 * 4);
    float*  w2d  = (float*)take(256 * 4);
    float*  a1s  = (float*)take(N_NODES * 4);
    float*  a1d  = (float*)take(N_NODES * 4);
    float*  a2s  = (float*)take(N_NODES * 4);
    float*  a2d  = (float*)take(N_NODES * 4);
    int*    deg  = (int*)take(N_NODES * 4);
    int*    offs = (int*)take((N_NODES + 4) * 4);
    int*    curs = (int*)take((N_NODES + 4) * 4);
    int*    bsum = (int*)take(1024);
    int*    esrc = (int*)take((size_t)ETOT * 4);
    (void)ws_size;

    hipMemsetAsync(deg, 0, N_NODES * sizeof(int), stream);

    int nbE = (ETOT + 255) / 256;
    int nbN = (N_NODES + 255) / 256;
    int nbW = (N_NODES * 64 + 255) / 256;       // one wave per node

    // CSR by dst
    k_deg<<<nbE, 256, 0, stream>>>(ei, deg);
    k_scan1<<<nbN, 256, 0, stream>>>(deg, offs, bsum);
    k_scan2<<<1, 256, 0, stream>>>(bsum, nbN);
    k_scan3<<<nbN, 256, 0, stream>>>(offs, bsum, curs);
    k_scatter<<<nbE, 256, 0, stream>>>(ei, curs, esrc);

    // weight prep: transpose+split, alpha GEMV vectors, x conversion + layer1 alphas
    k_splitT<<<(256 * 256 + 255) / 256, 256, 0, stream>>>(W1, w1th, w1tl, 256, 256);
    k_splitT<<<(256 * 128 + 255) / 256, 256, 0, stream>>>(W2, w2th, w2tl, 256, 128);
    k_wvec<<<256, 256, 0, stream>>>(W1, as1, ad1, W2, as2, ad2, w1s, w1d, w2s, w2d);
    k_prep1<<<nbW, 256, 0, stream>>>(x, w1s, w1d, xb, a1s, a1d);

    dim3 g1((N_NODES + 127) / 128, 2), g2((N_NODES + 127) / 128, 1);

    // ---- layer 1
    k_gemm_mfma<<<g1, 256, 0, stream>>>(xb, w1th, w1tl, h1b, N_NODES, 256);
    k_aggf<256, true, true, true><<<nbW, 256, 0, stream>>>(offs, esrc, a1s, a1d, h1b, b1,
                                                           out_h, hb, w2s, w2d, a2s, a2d);

    // ---- layer 2 (A = hb bf16; gb reuses h1b)
    ushort* gb = h1b;
    k_gemm_mfma<<<g2, 256, 0, stream>>>(hb, w2th, w2tl, gb, N_NODES, 128);
    k_aggf<128, false, false, false><<<nbW, 256, 0, stream>>>(offs, esrc, a2s, a2d, gb, b2,
                                                              out_x2, nullptr, nullptr, nullptr,
                                                              nullptr, nullptr);
}

// Round 20
// 267.784 us; speedup vs baseline: 1.4670x; 1.0182x over previous
//
#include <hip/hip_runtime.h>
#include <hip/hip_bf16.h>

#define N_NODES 50000
#define E0      800000
#define ETOT    850000

typedef __bf16 bf16x8 __attribute__((ext_vector_type(8)));
typedef float  f32x4  __attribute__((ext_vector_type(4)));
typedef ushort u16x8  __attribute__((ext_vector_type(8)));
typedef ushort u16x4  __attribute__((ext_vector_type(4)));
union B8 { u16x8 u; bf16x8 b; };

static __device__ __forceinline__ float b2f(ushort u) {
    union { uint u; float f; } x; x.u = ((uint)u) << 16; return x.f;
}
static __device__ __forceinline__ ushort f2bf(float f) {
    uint u = __builtin_bit_cast(uint, f);
    uint r = (u + 0x7FFFu + ((u >> 16) & 1u)) >> 16;   // RNE; inputs finite
    return (ushort)r;
}

// async global->LDS, 16B per lane (linear LDS: base + lane*16)
static __device__ __forceinline__ void gload16(const ushort* g, ushort* l) {
    __builtin_amdgcn_global_load_lds((const __attribute__((address_space(1))) unsigned int*)g,
                                     (__attribute__((address_space(3))) unsigned int*)l, 16, 0, 0);
}

// ---------------- CSR build ----------------

__global__ __launch_bounds__(256) void k_deg(const int* __restrict__ ei, int* __restrict__ deg) {
    int e = blockIdx.x * 256 + threadIdx.x;
    if (e >= ETOT) return;
    int dst = (e < E0) ? ei[E0 + e] : (e - E0);
    atomicAdd(&deg[dst], 1);
}

__global__ __launch_bounds__(256) void k_scan1(const int* __restrict__ deg, int* __restrict__ offs,
                                               int* __restrict__ bsum) {
    __shared__ int buf[256];
    int tid = threadIdx.x;
    int i = blockIdx.x * 256 + tid;
    int v = (i < N_NODES) ? deg[i] : 0;
    buf[tid] = v;
    __syncthreads();
    for (int off = 1; off < 256; off <<= 1) {
        int t = (tid >= off) ? buf[tid - off] : 0;
        __syncthreads();
        buf[tid] += t;
        __syncthreads();
    }
    if (i < N_NODES) offs[i + 1] = buf[tid];
    if (tid == 255) bsum[blockIdx.x] = buf[255];
}

__global__ __launch_bounds__(256) void k_scan2(int* __restrict__ bsum, int nb) {
    __shared__ int buf[256];
    int tid = threadIdx.x;
    int v = (tid < nb) ? bsum[tid] : 0;
    buf[tid] = v;
    __syncthreads();
    for (int off = 1; off < 256; off <<= 1) {
        int t = (tid >= off) ? buf[tid - off] : 0;
        __syncthreads();
        buf[tid] += t;
        __syncthreads();
    }
    if (tid < nb) bsum[tid] = buf[tid] - v;
}

// also fills cursor (saves a kernel)
__global__ __launch_bounds__(256) void k_scan3(int* __restrict__ offs, const int* __restrict__ bsum,
                                               int* __restrict__ cursor) {
    int tid = threadIdx.x;
    int i = blockIdx.x * 256 + tid;
    if (i < N_NODES) {
        int v = offs[i + 1] + bsum[blockIdx.x];
        offs[i + 1] = v;
        cursor[i + 1] = v;
    }
    if (i == 0) { offs[0] = 0; cursor[0] = 0; }
}

__global__ __launch_bounds__(256) void k_scatter(const int* __restrict__ ei, int* __restrict__ cursor,
                                                 int* __restrict__ esrc) {
    int e = blockIdx.x * 256 + threadIdx.x;
    if (e >= ETOT) return;
    int src, dst;
    if (e < E0) { src = ei[e]; dst = ei[E0 + e]; }
    else        { src = e - E0; dst = src; }
    int pos = atomicAdd(&cursor[dst], 1);
    esrc[pos] = src;
}

// ---- fused weight prep: W1/W2 transpose+split + alpha GEMV vectors ----
// blocks 0..255: splitT W1 ; 256..383: splitT W2 ; 384..639: wvec
__global__ __launch_bounds__(256) void k_wprep(const float* __restrict__ W1, const float* __restrict__ W2,
                                               const float* __restrict__ s1v, const float* __restrict__ d1v,
                                               const float* __restrict__ s2v, const float* __restrict__ d2v,
                                               ushort* __restrict__ w1th, ushort* __restrict__ w1tl,
                                               ushort* __restrict__ w2th, ushort* __restrict__ w2tl,
                                               float* __restrict__ w1s, float* __restrict__ w1d,
                                               float* __restrict__ w2s, float* __restrict__ w2d) {
    int b = blockIdx.x, t = threadIdx.x;
    if (b < 256) {
        int i = b * 256 + t;                    // 65536 = 256*256
        int n = i >> 8, k = i & 255;
        float v = W1[(size_t)k * 256 + n];
        ushort h = f2bf(v);
        w1th[(size_t)n * 256 + k] = h;
        w1tl[(size_t)n * 256 + k] = f2bf(v - b2f(h));
    } else if (b < 384) {
        int i = (b - 256) * 256 + t;            // 32768 = 256*128
        int n = i >> 8, k = i & 255;
        float v = W2[(size_t)k * 128 + n];
        ushort h = f2bf(v);
        w2th[(size_t)n * 256 + k] = h;          // note: w2t stride K=256
        w2tl[(size_t)n * 256 + k] = f2bf(v - b2f(h));
    } else {
        int gw = ((b - 384) * 256 + t) >> 6;    // 1024 waves
        int lane = t & 63;
        int vec = gw >> 8, kk = gw & 255;
        float a = 0.f;
        if (vec == 0)      { for (int n = lane; n < 256; n += 64) a += W1[(size_t)kk * 256 + n] * s1v[n]; }
        else if (vec == 1) { for (int n = lane; n < 256; n += 64) a += W1[(size_t)kk * 256 + n] * d1v[n]; }
        else if (vec == 2) { for (int n = lane; n < 128; n += 64) a += W2[(size_t)kk * 128 + n] * s2v[n]; }
        else               { for (int n = lane; n < 128; n += 64) a += W2[(size_t)kk * 128 + n] * d2v[n]; }
        for (int o = 32; o; o >>= 1) a += __shfl_down(a, o);
        if (lane == 0) {
            if (vec == 0) w1s[kk] = a;
            else if (vec == 1) w1d[kk] = a;
            else if (vec == 2) w2s[kk] = a;
            else w2d[kk] = a;
        }
    }
}

// one wave per row: x -> bf16 xb, plus layer1 alphas as1 = x.w1s, ad1 = x.w1d
__global__ __launch_bounds__(256) void k_prep1(const float* __restrict__ x, const float* __restrict__ w1s,
                                               const float* __restrict__ w1d, ushort* __restrict__ xb,
                                               float* __restrict__ as1, float* __restrict__ ad1) {
    int gw = (blockIdx.x * 256 + threadIdx.x) >> 6;
    int lane = threadIdx.x & 63;
    if (gw >= N_NODES) return;
    float4 v = *(const float4*)(x + (size_t)gw * 256 + lane * 4);
    ushort4 h;
    h.x = f2bf(v.x); h.y = f2bf(v.y); h.z = f2bf(v.z); h.w = f2bf(v.w);
    *(ushort4*)(xb + (size_t)gw * 256 + lane * 4) = h;
    float4 cs = *(const float4*)(w1s + lane * 4);
    float4 cd = *(const float4*)(w1d + lane * 4);
    float s = v.x * cs.x + v.y * cs.y + v.z * cs.z + v.w * cs.w;
    float d = v.x * cd.x + v.y * cd.y + v.z * cd.z + v.w * cd.w;
    for (int o = 32; o; o >>= 1) { s += __shfl_down(s, o); d += __shfl_down(d, o); }
    if (lane == 0) { as1[gw] = s; ad1[gw] = d; }
}

// ---------------- MFMA GEMM: m97-style async LDS staging [R19 — frozen] ----------------
// NOTE: B (w*th/w*tl) stored with stride 256 always; K loop count = K of the layer.

__global__ __launch_bounds__(256, 3) void k_gemm_mfma(const ushort* __restrict__ Ab,
                                                      const ushort* __restrict__ Bth,
                                                      const ushort* __restrict__ Btl,
                                                      ushort* __restrict__ Cb, int M, int Nn) {
    constexpr int K = 256;
    __shared__ ushort ldsA[2][128][32];          // 16 KB
    __shared__ ushort ldsB[2][2][128][32];       // 32 KB  [buf][hi/lo][col][k]
    int tid = threadIdx.x;
    int wid = tid >> 6, lane = tid & 63;
    int wr = wid >> 1, wc = wid & 1;
    int bm = blockIdx.x * 128, bn = blockIdx.y * 128;
    int lr = lane & 15, lg = lane >> 4;

    int srow = tid >> 2, sk = (tid & 3) << 3;
    const ushort* ga0  = Ab  + (size_t)(bm + srow) * K + sk;
    const ushort* ga1  = Ab  + (size_t)(bm + srow + 64) * K + sk;
    const ushort* gbh0 = Bth + (size_t)(bn + srow) * K + sk;
    const ushort* gbh1 = Bth + (size_t)(bn + srow + 64) * K + sk;
    const ushort* gbl0 = Btl + (size_t)(bn + srow) * K + sk;
    const ushort* gbl1 = Btl + (size_t)(bn + srow + 64) * K + sk;

#define STAGE(B, KT) do {                                   \
    gload16(ga0  + (KT), &ldsA[B][srow][sk]);               \
    gload16(ga1  + (KT), &ldsA[B][srow + 64][sk]);          \
    gload16(gbh0 + (KT), &ldsB[B][0][srow][sk]);            \
    gload16(gbh1 + (KT), &ldsB[B][0][srow + 64][sk]);       \
    gload16(gbl0 + (KT), &ldsB[B][1][srow][sk]);            \
    gload16(gbl1 + (KT), &ldsB[B][1][srow + 64][sk]);       \
} while (0)

    f32x4 acc[4][4] = {};

    STAGE(0, 0);
    __syncthreads();

#pragma unroll
    for (int s = 0; s < 8; ++s) {
        const int buf = s & 1;
        if (s < 7) STAGE(buf ^ 1, (s + 1) * 32);
        bf16x8 ah[4], bh[4], bl[4];
#pragma unroll
        for (int m = 0; m < 4; ++m)
            ah[m] = *(const bf16x8*)&ldsA[buf][wr * 64 + m * 16 + lr][lg * 8];
#pragma unroll
        for (int n = 0; n < 4; ++n) {
            bh[n] = *(const bf16x8*)&ldsB[buf][0][wc * 64 + n * 16 + lr][lg * 8];
            bl[n] = *(const bf16x8*)&ldsB[buf][1][wc * 64 + n * 16 + lr][lg * 8];
        }
#pragma unroll
        for (int m = 0; m < 4; ++m)
#pragma unroll
            for (int n = 0; n < 4; ++n) {
                acc[m][n] = __builtin_amdgcn_mfma_f32_16x16x32_bf16(ah[m], bh[n], acc[m][n], 0, 0, 0);
                acc[m][n] = __builtin_amdgcn_mfma_f32_16x16x32_bf16(ah[m], bl[n], acc[m][n], 0, 0, 0);
            }
        __syncthreads();
    }
#undef STAGE
    // C/D layout: col = lane&15, row = (lane>>4)*4 + reg   [m89-verified]
#pragma unroll
    for (int m = 0; m < 4; ++m)
#pragma unroll
        for (int r = 0; r < 4; ++r) {
            int row = bm + wr * 64 + m * 16 + lg * 4 + r;
            if (row < M) {
#pragma unroll
                for (int n = 0; n < 4; ++n) {
                    int col = bn + wc * 64 + n * 16 + lr;
                    Cb[(size_t)row * Nn + col] = f2bf(acc[m][n][r]);
                }
            }
        }
}

// ---- fused online-softmax aggregation: half-wave edge split ----
// Lanes 0-31 process even edges, 32-63 odd edges; each lane holds FL=F/32
// features. Uniform-scalar block (e/exp/ssum) halves vs full-wave version.
// Halves combined via shfl_xor(32) at end. A2/WB epilogues as before.
template <int F, bool RELU, bool WB, bool A2>
__global__ __launch_bounds__(256) void k_aggf(const int* __restrict__ offs, const int* __restrict__ esrc,
                                              const float* __restrict__ as, const float* __restrict__ ad,
                                              const ushort* __restrict__ H, const float* __restrict__ bias,
                                              float* __restrict__ out, ushort* __restrict__ hb,
                                              const float* __restrict__ w2s, const float* __restrict__ w2d,
                                              float* __restrict__ as2, float* __restrict__ ad2) {
    constexpr int FL = F / 32;                   // features per lane (8 or 4)
    constexpr float THR = 8.f;
    using Vec = typename std::conditional<FL == 8, u16x8, u16x4>::type;
    int gw = (blockIdx.x * 256 + threadIdx.x) >> 6;
    int lane = threadIdx.x & 63;
    int sub = lane >> 5, sl = lane & 31;
    if (gw >= N_NODES) return;
    int s0 = offs[gw], s1 = offs[gw + 1];
    float adi = ad[gw];
    float m = -1e30f, ssum = 0.f;
    float acc[FL] = {};
    const ushort* Hp = H + sl * FL;
    int k = s0;
    for (; k + 7 < s1; k += 8) {                 // 8 edges = 4 per half-wave
        int rr[4];
#pragma unroll
        for (int q = 0; q < 4; ++q) rr[q] = esrc[k + 2 * q + sub];
        float ev[4];
#pragma unroll
        for (int q = 0; q < 4; ++q) ev[q] = as[rr[q]];
        Vec rows[4];
#pragma unroll
        for (int q = 0; q < 4; ++q) rows[q] = *(const Vec*)(Hp + (size_t)rr[q] * F);
        float em = -1e30f;
#pragma unroll
        for (int q = 0; q < 4; ++q) {
            float e = ev[q] + adi;
            e = e > 0.f ? e : 0.2f * e;
            ev[q] = e;
            em = fmaxf(em, e);
        }
        em = fmaxf(em, __shfl_xor(em, 32));      // wave-uniform batch max
        if (em > m + THR) {
            float sc = __expf(m - em);
            ssum *= sc;
#pragma unroll
            for (int j = 0; j < FL; ++j) acc[j] *= sc;
            m = em;
        }
        float w[4];
#pragma unroll
        for (int q = 0; q < 4; ++q) w[q] = __expf(ev[q] - m);
#pragma unroll
        for (int q = 0; q < 4; ++q) ssum += w[q];
#pragma unroll
        for (int j = 0; j < FL; ++j) {
            float a = acc[j];
#pragma unroll
            for (int q = 0; q < 4; ++q) a += w[q] * b2f(rows[q][j]);
            acc[j] = a;
        }
    }
    for (; k < s1; k += 2) {                     // remainder: 1 edge per half
        int idx = k + sub;
        bool val = idx < s1;
        int r0 = esrc[val ? idx : s1 - 1];
        Vec v = *(const Vec*)(Hp + (size_t)r0 * F);
        float e = as[r0] + adi;
        e = e > 0.f ? e : 0.2f * e;
        if (!val) e = -3e30f;
        float em = fmaxf(e, __shfl_xor(e, 32));
        if (em > m + THR) {
            float sc = __expf(m - em);
            ssum *= sc;
#pragma unroll
            for (int j = 0; j < FL; ++j) acc[j] *= sc;
            m = em;
        }
        float w0 = val ? __expf(e - m) : 0.f;
        ssum += w0;
#pragma unroll
        for (int j = 0; j < FL; ++j) acc[j] += w0 * b2f(v[j]);
    }
    // combine half-waves
#pragma unroll
    for (int j = 0; j < FL; ++j) acc[j] += __shfl_xor(acc[j], 32);
    ssum += __shfl_xor(ssum, 32);

    float inv = 1.f / ssum;
    float r[FL];
#pragma unroll
    for (int j = 0; j < FL; ++j) {
        r[j] = acc[j] * inv + bias[sl * FL + j];
        if (RELU) r[j] = fmaxf(r[j], 0.f);
    }
    if (sub == 0) {
        if constexpr (FL == 8) {
            *(float4*)(out + (size_t)gw * F + sl * 8)     = make_float4(r[0], r[1], r[2], r[3]);
            *(float4*)(out + (size_t)gw * F + sl * 8 + 4) = make_float4(r[4], r[5], r[6], r[7]);
        } else {
            *(float4*)(out + (size_t)gw * F + sl * 4) = make_float4(r[0], r[1], r[2], r[3]);
        }
        if constexpr (WB && FL == 8) {
            u16x8 hv;
#pragma unroll
            for (int j = 0; j < 8; ++j) hv[j] = f2bf(r[j]);
            *(u16x8*)(hb + (size_t)gw * F + sl * 8) = hv;
        }
    }
    if constexpr (A2 && FL == 8) {
        float s2 = 0.f, d2 = 0.f;
#pragma unroll
        for (int j = 0; j < 8; ++j) {
            s2 += r[j] * w2s[sl * 8 + j];
            d2 += r[j] * w2d[sl * 8 + j];
        }
        for (int o = 16; o; o >>= 1) { s2 += __shfl_down(s2, o, 32); d2 += __shfl_down(d2, o, 32); }
        if (lane == 0) { as2[gw] = s2; ad2[gw] = d2; }
    }
}

// ---------------- launch ----------------

static inline size_t al256(size_t x) { return (x + 255) & ~(size_t)255; }

extern "C" void kernel_launch(void* const* d_in, const int* in_sizes, int n_in,
                              void* d_out, int out_size, void* d_ws, size_t ws_size,
                              hipStream_t stream) {
    const float* x   = (const float*)d_in[0];
    const int*   ei  = (const int*)d_in[1];
    const float* W1  = (const float*)d_in[2];
    const float* as1 = (const float*)d_in[3];
    const float* ad1 = (const float*)d_in[4];
    const float* b1  = (const float*)d_in[5];
    const float* W2  = (const float*)d_in[6];
    const float* as2 = (const float*)d_in[7];
    const float* ad2 = (const float*)d_in[8];
    const float* b2  = (const float*)d_in[9];

    float* out_x2 = (float*)d_out;                          // [50000,128]
    float* out_h  = (float*)d_out + (size_t)N_NODES * 128;  // [50000,256] fp32

    const size_t NM256 = (size_t)N_NODES * 256 * 2;         // bf16 [50000][256]
    const size_t PAD   = (size_t)128 * 256 * 2;             // GEMM A staging pad rows
    char* base = (char*)d_ws;
    size_t off = 0;
    auto take = [&](size_t bytes) { char* p = base + off; off = al256(off + bytes); return p; };

    ushort* h1b  = (ushort*)take(NM256);            // layer1 GEMM out (bf16); reused as layer2 gb
    ushort* xb   = (ushort*)take(NM256 + PAD);      // RNE bf16 of x (+pad for staging reads)
    ushort* hb   = (ushort*)take(NM256 + PAD);      // RNE bf16 of relu(out_h) (+pad)
    ushort* w1th = (ushort*)take(256 * 256 * 2);
    ushort* w1tl = (ushort*)take(256 * 256 * 2);
    ushort* w2th = (ushort*)take(256 * 256 * 2);    // stride-256 layout (K=256)
    ushort* w2tl = (ushort*)take(256 * 256 * 2);
    float*  w1s  = (float*)take(256 * 4);
    float*  w1d  = (float*)take(256 * 4);
    float*  w2s  = (float*)take(256 * 4);
    float*  w2d  = (float*)take(256 * 4);
    float*  a1s  = (float*)take(N_NODES * 4);
    float*  a1d  = (float*)take(N_NODES * 4);
    float*  a2s  = (float*)take(N_NODES * 4);
    float*  a2d  = (float*)take(N_NODES * 4);
    int*    deg  = (int*)take(N_NODES * 4);
    int*    offs = (int*)take((N_NODES + 4) * 4);
    int*    curs = (int*)take((N_NODES + 4) * 4);
    int*    bsum = (int*)take(1024);
    int*    esrc = (int*)take((size_t)ETOT * 4);
    (void)ws_size;

    hipMemsetAsync(deg, 0, N_NODES * sizeof(int), stream);

    int nbE = (ETOT + 255) / 256;
    int nbN = (N_NODES + 255) / 256;
    int nbW = (N_NODES * 64 + 255) / 256;       // one wave per node

    // CSR by dst
    k_deg<<<nbE, 256, 0, stream>>>(ei, deg);
    k_scan1<<<nbN, 256, 0, stream>>>(deg, offs, bsum);
    k_scan2<<<1, 256, 0, stream>>>(bsum, nbN);
    k_scan3<<<nbN, 256, 0, stream>>>(offs, bsum, curs);
    k_scatter<<<nbE, 256, 0, stream>>>(ei, curs, esrc);

    // fused weight prep + x conversion/alphas
    k_wprep<<<640, 256, 0, stream>>>(W1, W2, as1, ad1, as2, ad2,
                                     w1th, w1tl, w2th, w2tl, w1s, w1d, w2s, w2d);
    k_prep1<<<nbW, 256, 0, stream>>>(x, w1s, w1d, xb, a1s, a1d);

    dim3 g1((N_NODES + 127) / 128, 2), g2((N_NODES + 127) / 128, 1);

    // ---- layer 1
    k_gemm_mfma<<<g1, 256, 0, stream>>>(xb, w1th, w1tl, h1b, N_NODES, 256);
    k_aggf<256, true, true, true><<<nbW, 256, 0, stream>>>(offs, esrc, a1s, a1d, h1b, b1,
                                                           out_h, hb, w2s, w2d, a2s, a2d);

    // ---- layer 2 (A = hb bf16; gb reuses h1b)
    ushort* gb = h1b;
    k_gemm_mfma<<<g2, 256, 0, stream>>>(hb, w2th, w2tl, gb, N_NODES, 128);
    k_aggf<128, false, false, false><<<nbW, 256, 0, stream>>>(offs, esrc, a2s, a2d, gb, b2,
                                                              out_x2, nullptr, nullptr, nullptr,
                                                              nullptr, nullptr);
}

// Round 21
// 266.341 us; speedup vs baseline: 1.4749x; 1.0054x over previous
//
#include <hip/hip_runtime.h>
#include <hip/hip_bf16.h>

#define N_NODES 50000
#define E0      800000
#define ETOT    850000

typedef __bf16 bf16x8 __attribute__((ext_vector_type(8)));
typedef float  f32x4  __attribute__((ext_vector_type(4)));
typedef ushort u16x8  __attribute__((ext_vector_type(8)));
typedef ushort u16x4  __attribute__((ext_vector_type(4)));
union B8 { u16x8 u; bf16x8 b; };

static __device__ __forceinline__ float b2f(ushort u) {
    union { uint u; float f; } x; x.u = ((uint)u) << 16; return x.f;
}
static __device__ __forceinline__ ushort f2bf(float f) {
    uint u = __builtin_bit_cast(uint, f);
    uint r = (u + 0x7FFFu + ((u >> 16) & 1u)) >> 16;   // RNE; inputs finite
    return (ushort)r;
}

// async global->LDS, 16B per lane (linear LDS: base + lane*16)
static __device__ __forceinline__ void gload16(const ushort* g, ushort* l) {
    __builtin_amdgcn_global_load_lds((const __attribute__((address_space(1))) unsigned int*)g,
                                     (__attribute__((address_space(3))) unsigned int*)l, 16, 0, 0);
}

// ---------------- CSR build ----------------

__global__ __launch_bounds__(256) void k_deg(const int* __restrict__ ei, int* __restrict__ deg) {
    int e = blockIdx.x * 256 + threadIdx.x;
    if (e >= ETOT) return;
    int dst = (e < E0) ? ei[E0 + e] : (e - E0);
    atomicAdd(&deg[dst], 1);
}

__global__ __launch_bounds__(256) void k_scan1(const int* __restrict__ deg, int* __restrict__ offs,
                                               int* __restrict__ bsum) {
    __shared__ int buf[256];
    int tid = threadIdx.x;
    int i = blockIdx.x * 256 + tid;
    int v = (i < N_NODES) ? deg[i] : 0;
    buf[tid] = v;
    __syncthreads();
    for (int off = 1; off < 256; off <<= 1) {
        int t = (tid >= off) ? buf[tid - off] : 0;
        __syncthreads();
        buf[tid] += t;
        __syncthreads();
    }
    if (i < N_NODES) offs[i + 1] = buf[tid];
    if (tid == 255) bsum[blockIdx.x] = buf[255];
}

// fused scan2+scan3: each block redundantly scans bsum (nbN<=256), applies its
// exclusive prefix, and fills cursor.
__global__ __launch_bounds__(256) void k_scan23(int* __restrict__ offs, const int* __restrict__ bsum,
                                                int* __restrict__ cursor, int nb) {
    __shared__ int buf[256];
    int tid = threadIdx.x;
    int v = (tid < nb) ? bsum[tid] : 0;
    buf[tid] = v;
    __syncthreads();
    for (int off = 1; off < 256; off <<= 1) {
        int t = (tid >= off) ? buf[tid - off] : 0;
        __syncthreads();
        buf[tid] += t;
        __syncthreads();
    }
    int boff = (blockIdx.x == 0) ? 0 : buf[blockIdx.x - 1];
    int i = blockIdx.x * 256 + tid;
    if (i < N_NODES) {
        int val = offs[i + 1] + boff;
        offs[i + 1] = val;
        cursor[i + 1] = val;
    }
    if (i == 0) { offs[0] = 0; cursor[0] = 0; }
}

__global__ __launch_bounds__(256) void k_scatter(const int* __restrict__ ei, int* __restrict__ cursor,
                                                 int* __restrict__ esrc) {
    int e = blockIdx.x * 256 + threadIdx.x;
    if (e >= ETOT) return;
    int src, dst;
    if (e < E0) { src = ei[e]; dst = ei[E0 + e]; }
    else        { src = e - E0; dst = src; }
    int pos = atomicAdd(&cursor[dst], 1);
    esrc[pos] = src;
}

// ---- fused prep: W1/W2 transpose+split + alpha GEMV vectors + x->bf16/alphas ----
// blocks 0..255: splitT W1 ; 256..383: splitT W2 ; 384..639: wvec ;
// 640.. : per-node x conversion + layer1 alphas (reads w1s/w1d written by wvec
// blocks — ordering hazard avoided: prep1 part recomputes the two needed dot
// vectors? No — instead prep1 blocks compute alphas from x and W1 GEMV vecs
// passed via global; to keep correctness WITHOUT inter-block ordering, the
// prep1 part does NOT read w1s/w1d: it computes as1/ad1 directly as
// (x row) . (W1 a1vec) using precomputed vectors is required... so we keep
// prep1 reading w1s/w1d but launched as a SEPARATE kernel to preserve the
// dependency. Only wprep's three parts are fused here.
__global__ __launch_bounds__(256) void k_wprep(const float* __restrict__ W1, const float* __restrict__ W2,
                                               const float* __restrict__ s1v, const float* __restrict__ d1v,
                                               const float* __restrict__ s2v, const float* __restrict__ d2v,
                                               ushort* __restrict__ w1th, ushort* __restrict__ w1tl,
                                               ushort* __restrict__ w2th, ushort* __restrict__ w2tl,
                                               float* __restrict__ w1s, float* __restrict__ w1d,
                                               float* __restrict__ w2s, float* __restrict__ w2d) {
    int b = blockIdx.x, t = threadIdx.x;
    if (b < 256) {
        int i = b * 256 + t;
        int n = i >> 8, k = i & 255;
        float v = W1[(size_t)k * 256 + n];
        ushort h = f2bf(v);
        w1th[(size_t)n * 256 + k] = h;
        w1tl[(size_t)n * 256 + k] = f2bf(v - b2f(h));
    } else if (b < 384) {
        int i = (b - 256) * 256 + t;
        int n = i >> 8, k = i & 255;
        float v = W2[(size_t)k * 128 + n];
        ushort h = f2bf(v);
        w2th[(size_t)n * 256 + k] = h;          // stride-256 layout
        w2tl[(size_t)n * 256 + k] = f2bf(v - b2f(h));
    } else {
        int gw = ((b - 384) * 256 + t) >> 6;
        int lane = t & 63;
        int vec = gw >> 8, kk = gw & 255;
        float a = 0.f;
        if (vec == 0)      { for (int n = lane; n < 256; n += 64) a += W1[(size_t)kk * 256 + n] * s1v[n]; }
        else if (vec == 1) { for (int n = lane; n < 256; n += 64) a += W1[(size_t)kk * 256 + n] * d1v[n]; }
        else if (vec == 2) { for (int n = lane; n < 128; n += 64) a += W2[(size_t)kk * 128 + n] * s2v[n]; }
        else               { for (int n = lane; n < 128; n += 64) a += W2[(size_t)kk * 128 + n] * d2v[n]; }
        for (int o = 32; o; o >>= 1) a += __shfl_down(a, o);
        if (lane == 0) {
            if (vec == 0) w1s[kk] = a;
            else if (vec == 1) w1d[kk] = a;
            else if (vec == 2) w2s[kk] = a;
            else w2d[kk] = a;
        }
    }
}

// one wave per row: x -> bf16 xb, plus layer1 alphas as1 = x.w1s, ad1 = x.w1d
__global__ __launch_bounds__(256) void k_prep1(const float* __restrict__ x, const float* __restrict__ w1s,
                                               const float* __restrict__ w1d, ushort* __restrict__ xb,
                                               float* __restrict__ as1, float* __restrict__ ad1) {
    int gw = (blockIdx.x * 256 + threadIdx.x) >> 6;
    int lane = threadIdx.x & 63;
    if (gw >= N_NODES) return;
    float4 v = *(const float4*)(x + (size_t)gw * 256 + lane * 4);
    ushort4 h;
    h.x = f2bf(v.x); h.y = f2bf(v.y); h.z = f2bf(v.z); h.w = f2bf(v.w);
    *(ushort4*)(xb + (size_t)gw * 256 + lane * 4) = h;
    float4 cs = *(const float4*)(w1s + lane * 4);
    float4 cd = *(const float4*)(w1d + lane * 4);
    float s = v.x * cs.x + v.y * cs.y + v.z * cs.z + v.w * cs.w;
    float d = v.x * cd.x + v.y * cd.y + v.z * cd.z + v.w * cd.w;
    for (int o = 32; o; o >>= 1) { s += __shfl_down(s, o); d += __shfl_down(d, o); }
    if (lane == 0) { as1[gw] = s; ad1[gw] = d; }
}

// ---------------- MFMA GEMM: m97-style async LDS staging [R19 — frozen] ----------------

__global__ __launch_bounds__(256, 3) void k_gemm_mfma(const ushort* __restrict__ Ab,
                                                      const ushort* __restrict__ Bth,
                                                      const ushort* __restrict__ Btl,
                                                      ushort* __restrict__ Cb, int M, int Nn) {
    constexpr int K = 256;
    __shared__ ushort ldsA[2][128][32];          // 16 KB
    __shared__ ushort ldsB[2][2][128][32];       // 32 KB  [buf][hi/lo][col][k]
    int tid = threadIdx.x;
    int wid = tid >> 6, lane = tid & 63;
    int wr = wid >> 1, wc = wid & 1;
    int bm = blockIdx.x * 128, bn = blockIdx.y * 128;
    int lr = lane & 15, lg = lane >> 4;

    int srow = tid >> 2, sk = (tid & 3) << 3;
    const ushort* ga0  = Ab  + (size_t)(bm + srow) * K + sk;
    const ushort* ga1  = Ab  + (size_t)(bm + srow + 64) * K + sk;
    const ushort* gbh0 = Bth + (size_t)(bn + srow) * K + sk;
    const ushort* gbh1 = Bth + (size_t)(bn + srow + 64) * K + sk;
    const ushort* gbl0 = Btl + (size_t)(bn + srow) * K + sk;
    const ushort* gbl1 = Btl + (size_t)(bn + srow + 64) * K + sk;

#define STAGE(B, KT) do {                                   \
    gload16(ga0  + (KT), &ldsA[B][srow][sk]);               \
    gload16(ga1  + (KT), &ldsA[B][srow + 64][sk]);          \
    gload16(gbh0 + (KT), &ldsB[B][0][srow][sk]);            \
    gload16(gbh1 + (KT), &ldsB[B][0][srow + 64][sk]);       \
    gload16(gbl0 + (KT), &ldsB[B][1][srow][sk]);            \
    gload16(gbl1 + (KT), &ldsB[B][1][srow + 64][sk]);       \
} while (0)

    f32x4 acc[4][4] = {};

    STAGE(0, 0);
    __syncthreads();

#pragma unroll
    for (int s = 0; s < 8; ++s) {
        const int buf = s & 1;
        if (s < 7) STAGE(buf ^ 1, (s + 1) * 32);
        bf16x8 ah[4], bh[4], bl[4];
#pragma unroll
        for (int m = 0; m < 4; ++m)
            ah[m] = *(const bf16x8*)&ldsA[buf][wr * 64 + m * 16 + lr][lg * 8];
#pragma unroll
        for (int n = 0; n < 4; ++n) {
            bh[n] = *(const bf16x8*)&ldsB[buf][0][wc * 64 + n * 16 + lr][lg * 8];
            bl[n] = *(const bf16x8*)&ldsB[buf][1][wc * 64 + n * 16 + lr][lg * 8];
        }
#pragma unroll
        for (int m = 0; m < 4; ++m)
#pragma unroll
            for (int n = 0; n < 4; ++n) {
                acc[m][n] = __builtin_amdgcn_mfma_f32_16x16x32_bf16(ah[m], bh[n], acc[m][n], 0, 0, 0);
                acc[m][n] = __builtin_amdgcn_mfma_f32_16x16x32_bf16(ah[m], bl[n], acc[m][n], 0, 0, 0);
            }
        __syncthreads();
    }
#undef STAGE
    // C/D layout: col = lane&15, row = (lane>>4)*4 + reg   [m89-verified]
#pragma unroll
    for (int m = 0; m < 4; ++m)
#pragma unroll
        for (int r = 0; r < 4; ++r) {
            int row = bm + wr * 64 + m * 16 + lg * 4 + r;
            if (row < M) {
#pragma unroll
                for (int n = 0; n < 4; ++n) {
                    int col = bn + wc * 64 + n * 16 + lr;
                    Cb[(size_t)row * Nn + col] = f2bf(acc[m][n][r]);
                }
            }
        }
}

// ---- fused online-softmax aggregation: half-wave edge split [R20 — frozen] ----
template <int F, bool RELU, bool WB, bool A2>
__global__ __launch_bounds__(256) void k_aggf(const int* __restrict__ offs, const int* __restrict__ esrc,
                                              const float* __restrict__ as, const float* __restrict__ ad,
                                              const ushort* __restrict__ H, const float* __restrict__ bias,
                                              float* __restrict__ out, ushort* __restrict__ hb,
                                              const float* __restrict__ w2s, const float* __restrict__ w2d,
                                              float* __restrict__ as2, float* __restrict__ ad2) {
    constexpr int FL = F / 32;                   // features per lane (8 or 4)
    constexpr float THR = 8.f;
    using Vec = typename std::conditional<FL == 8, u16x8, u16x4>::type;
    int gw = (blockIdx.x * 256 + threadIdx.x) >> 6;
    int lane = threadIdx.x & 63;
    int sub = lane >> 5, sl = lane & 31;
    if (gw >= N_NODES) return;
    int s0 = offs[gw], s1 = offs[gw + 1];
    float adi = ad[gw];
    float m = -1e30f, ssum = 0.f;
    float acc[FL] = {};
    const ushort* Hp = H + sl * FL;
    int k = s0;
    for (; k + 7 < s1; k += 8) {                 // 8 edges = 4 per half-wave
        int rr[4];
#pragma unroll
        for (int q = 0; q < 4; ++q) rr[q] = esrc[k + 2 * q + sub];
        float ev[4];
#pragma unroll
        for (int q = 0; q < 4; ++q) ev[q] = as[rr[q]];
        Vec rows[4];
#pragma unroll
        for (int q = 0; q < 4; ++q) rows[q] = *(const Vec*)(Hp + (size_t)rr[q] * F);
        float em = -1e30f;
#pragma unroll
        for (int q = 0; q < 4; ++q) {
            float e = ev[q] + adi;
            e = e > 0.f ? e : 0.2f * e;
            ev[q] = e;
            em = fmaxf(em, e);
        }
        em = fmaxf(em, __shfl_xor(em, 32));      // wave-uniform batch max
        if (em > m + THR) {
            float sc = __expf(m - em);
            ssum *= sc;
#pragma unroll
            for (int j = 0; j < FL; ++j) acc[j] *= sc;
            m = em;
        }
        float w[4];
#pragma unroll
        for (int q = 0; q < 4; ++q) w[q] = __expf(ev[q] - m);
#pragma unroll
        for (int q = 0; q < 4; ++q) ssum += w[q];
#pragma unroll
        for (int j = 0; j < FL; ++j) {
            float a = acc[j];
#pragma unroll
            for (int q = 0; q < 4; ++q) a += w[q] * b2f(rows[q][j]);
            acc[j] = a;
        }
    }
    for (; k < s1; k += 2) {                     // remainder: 1 edge per half
        int idx = k + sub;
        bool val = idx < s1;
        int r0 = esrc[val ? idx : s1 - 1];
        Vec v = *(const Vec*)(Hp + (size_t)r0 * F);
        float e = as[r0] + adi;
        e = e > 0.f ? e : 0.2f * e;
        if (!val) e = -3e30f;
        float em = fmaxf(e, __shfl_xor(e, 32));
        if (em > m + THR) {
            float sc = __expf(m - em);
            ssum *= sc;
#pragma unroll
            for (int j = 0; j < FL; ++j) acc[j] *= sc;
            m = em;
        }
        float w0 = val ? __expf(e - m) : 0.f;
        ssum += w0;
#pragma unroll
        for (int j = 0; j < FL; ++j) acc[j] += w0 * b2f(v[j]);
    }
    // combine half-waves
#pragma unroll
    for (int j = 0; j < FL; ++j) acc[j] += __shfl_xor(acc[j], 32);
    ssum += __shfl_xor(ssum, 32);

    float inv = 1.f / ssum;
    float r[FL];
#pragma unroll
    for (int j = 0; j < FL; ++j) {
        r[j] = acc[j] * inv + bias[sl * FL + j];
        if (RELU) r[j] = fmaxf(r[j], 0.f);
    }
    if (sub == 0) {
        if constexpr (FL == 8) {
            *(float4*)(out + (size_t)gw * F + sl * 8)     = make_float4(r[0], r[1], r[2], r[3]);
            *(float4*)(out + (size_t)gw * F + sl * 8 + 4) = make_float4(r[4], r[5], r[6], r[7]);
        } else {
            *(float4*)(out + (size_t)gw * F + sl * 4) = make_float4(r[0], r[1], r[2], r[3]);
        }
        if constexpr (WB && FL == 8) {
            u16x8 hv;
#pragma unroll
            for (int j = 0; j < 8; ++j) hv[j] = f2bf(r[j]);
            *(u16x8*)(hb + (size_t)gw * F + sl * 8) = hv;
        }
    }
    if constexpr (A2 && FL == 8) {
        float s2 = 0.f, d2 = 0.f;
#pragma unroll
        for (int j = 0; j < 8; ++j) {
            s2 += r[j] * w2s[sl * 8 + j];
            d2 += r[j] * w2d[sl * 8 + j];
        }
        for (int o = 16; o; o >>= 1) { s2 += __shfl_down(s2, o, 32); d2 += __shfl_down(d2, o, 32); }
        if (lane == 0) { as2[gw] = s2; ad2[gw] = d2; }
    }
}

// ---------------- launch ----------------

static inline size_t al256(size_t x) { return (x + 255) & ~(size_t)255; }

extern "C" void kernel_launch(void* const* d_in, const int* in_sizes, int n_in,
                              void* d_out, int out_size, void* d_ws, size_t ws_size,
                              hipStream_t stream) {
    const float* x   = (const float*)d_in[0];
    const int*   ei  = (const int*)d_in[1];
    const float* W1  = (const float*)d_in[2];
    const float* as1 = (const float*)d_in[3];
    const float* ad1 = (const float*)d_in[4];
    const float* b1  = (const float*)d_in[5];
    const float* W2  = (const float*)d_in[6];
    const float* as2 = (const float*)d_in[7];
    const float* ad2 = (const float*)d_in[8];
    const float* b2  = (const float*)d_in[9];

    float* out_x2 = (float*)d_out;                          // [50000,128]
    float* out_h  = (float*)d_out + (size_t)N_NODES * 128;  // [50000,256] fp32

    const size_t NM256 = (size_t)N_NODES * 256 * 2;         // bf16 [50000][256]
    const size_t PAD   = (size_t)128 * 256 * 2;             // GEMM A staging pad rows
    char* base = (char*)d_ws;
    size_t off = 0;
    auto take = [&](size_t bytes) { char* p = base + off; off = al256(off + bytes); return p; };

    ushort* h1b  = (ushort*)take(NM256);            // layer1 GEMM out (bf16); reused as layer2 gb
    ushort* xb   = (ushort*)take(NM256 + PAD);      // RNE bf16 of x (+pad for staging reads)
    ushort* hb   = (ushort*)take(NM256 + PAD);      // RNE bf16 of relu(out_h) (+pad)
    ushort* w1th = (ushort*)take(256 * 256 * 2);
    ushort* w1tl = (ushort*)take(256 * 256 * 2);
    ushort* w2th = (ushort*)take(256 * 256 * 2);    // stride-256 layout (K=256)
    ushort* w2tl = (ushort*)take(256 * 256 * 2);
    float*  w1s  = (float*)take(256 * 4);
    float*  w1d  = (float*)take(256 * 4);
    float*  w2s  = (float*)take(256 * 4);
    float*  w2d  = (float*)take(256 * 4);
    float*  a1s  = (float*)take(N_NODES * 4);
    float*  a1d  = (float*)take(N_NODES * 4);
    float*  a2s  = (float*)take(N_NODES * 4);
    float*  a2d  = (float*)take(N_NODES * 4);
    int*    deg  = (int*)take(N_NODES * 4);
    int*    offs = (int*)take((N_NODES + 4) * 4);
    int*    curs = (int*)take((N_NODES + 4) * 4);
    int*    bsum = (int*)take(1024);
    int*    esrc = (int*)take((size_t)ETOT * 4);
    (void)ws_size;

    hipMemsetAsync(deg, 0, N_NODES * sizeof(int), stream);

    int nbE = (ETOT + 255) / 256;
    int nbN = (N_NODES + 255) / 256;            // 196 (<=256 for k_scan23)
    int nbW = (N_NODES * 64 + 255) / 256;       // one wave per node

    // CSR by dst (scan2 fused into scan23)
    k_deg<<<nbE, 256, 0, stream>>>(ei, deg);
    k_scan1<<<nbN, 256, 0, stream>>>(deg, offs, bsum);
    k_scan23<<<nbN, 256, 0, stream>>>(offs, bsum, curs, nbN);
    k_scatter<<<nbE, 256, 0, stream>>>(ei, curs, esrc);

    // weight prep + x conversion/alphas
    k_wprep<<<640, 256, 0, stream>>>(W1, W2, as1, ad1, as2, ad2,
                                     w1th, w1tl, w2th, w2tl, w1s, w1d, w2s, w2d);
    k_prep1<<<nbW, 256, 0, stream>>>(x, w1s, w1d, xb, a1s, a1d);

    dim3 g1((N_NODES + 127) / 128, 2), g2((N_NODES + 127) / 128, 1);

    // ---- layer 1
    k_gemm_mfma<<<g1, 256, 0, stream>>>(xb, w1th, w1tl, h1b, N_NODES, 256);
    k_aggf<256, true, true, true><<<nbW, 256, 0, stream>>>(offs, esrc, a1s, a1d, h1b, b1,
                                                           out_h, hb, w2s, w2d, a2s, a2d);

    // ---- layer 2 (A = hb bf16; gb reuses h1b)
    ushort* gb = h1b;
    k_gemm_mfma<<<g2, 256, 0, stream>>>(hb, w2th, w2tl, gb, N_NODES, 128);
    k_aggf<128, false, false, false><<<nbW, 256, 0, stream>>>(offs, esrc, a2s, a2d, gb, b2,
                                                              out_x2, nullptr, nullptr, nullptr,
                                                              nullptr, nullptr);
}